// Round 12
// baseline (1066.249 us; speedup 1.0000x reference)
//
#include <hip/hip_runtime.h>
#include <hip/hip_bf16.h>
#include <hip/hip_fp16.h>

#define DD 32
constexpr int N_ = 200000;
constexpr int E_ = 3200000;
constexpr int B_ = 512;

typedef _Float16 f16x4 __attribute__((ext_vector_type(4)));
typedef float f32x4 __attribute__((ext_vector_type(4)));

// ---------------- workspace layout ----------------
constexpr int OFF_EMB=0, OFF_B0=3232, OFF_BIHG=3264, OFF_BHHG=3360, OFF_BIH0=3456,
  OFF_BHH0=3584, OFF_BIH12=3712, OFF_BHH12=3968, OFF_BR1=4224, OFF_BR2=4256,
  OFF_W0T=4288, OFF_WMT=5312, OFF_WIHGT=6336, OFF_WHHGT=9408,
  OFF_WIH0T=12480, OFF_WHH0T=20672, OFF_WIH1T=24768, OFF_WHH1T=28864,
  OFF_WIH2T=32960, OFF_WHH2T=37056, OFF_WR1T=41152, OFF_WR2T=43200;
constexpr long FLOAT_END=44288L;
// fp16 MFMA weight-fragment region (6144 halfs = 12288 B), then fp16 states
constexpr size_t F16_BYTE = (size_t)FLOAT_END*4;           // 177152
constexpr size_t H0_BYTE  = F16_BYTE + 12288;              // 189440
constexpr size_t H1_BYTE  = H0_BYTE + (size_t)N_*DD*2;     // fp16 state B
constexpr size_t INT_BASE = H1_BYTE + (size_t)N_*DD*2;     // 25789440, 256B aligned
// int offsets (in ints, from INT_BASE)
constexpr int I_DEG=0, I_NOFF=200512, I_CURSOR=400512, I_GOFF=600512,
  I_BSUM=601088, I_BOFF=601344, I_CSR=601600;      // csr: E ints
constexpr int I_FLAG=3801600;

__device__ __forceinline__ float bf2f(unsigned short u){ return __uint_as_float(((unsigned)u)<<16); }
__device__ __forceinline__ float sigm(float x){ return 1.0f/(1.0f+__expf(-x)); }
__device__ __forceinline__ float tanhfast(float x){ return 1.0f - 2.0f/(__expf(2.0f*x)+1.0f); }

// ---------------- input-dtype detection ----------------
__global__ void k_detect(const unsigned int* __restrict__ emb_raw, int* __restrict__ flag){
  if(threadIdx.x==0){
    unsigned v=0;
    for(int i=16;i<32;i++) v |= emb_raw[i];
    flag[0] = v ? 1 : 0;   // 1 = bf16 inputs, 0 = f32 inputs
  }
}

// -------- weight prep: (bf16|f32) -> fp32 ------------------------------------------
struct PrepArgs { const void* s[22]; int off[22]; int sz[22]; int trR[22]; int soff[22]; int pk[22]; };

__global__ void k_prep(PrepArgs a, float* __restrict__ W, const int* __restrict__ flag){
  int bf = flag[0];
  int seg = blockIdx.y;
  int i = blockIdx.x*256 + threadIdx.x;
  if(i >= a.sz[seg]) return;
  int R = a.trR[seg];
  int P = a.pk[seg];
  int sidx;
  if(P){
    int c = i/(4*P); int rem = i%(4*P); int col = rem>>2; int s = rem&3;
    sidx = col*DD + 4*c + s;
  } else if(R){ int C = a.sz[seg]/R; sidx = (i%R)*C + (i/R); } else sidx = i;
  sidx += a.soff[seg];
  float v = bf ? bf2f(((const unsigned short*)a.s[seg])[sidx])
               : ((const float*)a.s[seg])[sidx];
  W[a.off[seg]+i] = v;
}

// ---- pack GRU gate weights into fp16 MFMA B-fragments (16x16x16f16 layout) ----
__global__ void k_prep16(const float* __restrict__ Wall, __half* __restrict__ F){
  int id = blockIdx.x*256 + threadIdx.x;
  if(id >= 6144) return;
  int e  = id & 3;
  int l  = (id >> 2) & 63;
  int kh = (id >> 8) & 1;
  int tmp = id >> 9;
  int jt  = tmp % 6;
  int reg = tmp / 6;
  int j = 16*jt + (l & 15);
  int k = 16*kh + 4*(l >> 4) + e;
  int srcoff = (reg==0 ? OFF_WIHGT : OFF_WHHGT) + j*DD + k;
  F[id] = __float2half(Wall[srcoff]);
}

// ---------------- lin0: h0[n] = fp16(relu(W0 @ emb[node_type[n]] + b0)) -----------
__global__ void k_lin0(const int* __restrict__ nt, const float* __restrict__ Wall,
                       __half* __restrict__ hmir){
  int n = blockIdx.x*blockDim.x + threadIdx.x;
  if(n >= N_) return;
  const float* er  = Wall + OFF_EMB + nt[n]*DD;
  const float* W0T = Wall + OFF_W0T;
  const float* b0  = Wall + OFF_B0;
  float m[DD];
  #pragma unroll
  for(int j=0;j<DD;j++) m[j]=b0[j];
  #pragma unroll 4
  for(int k=0;k<DD;k++){
    float xk = er[k];
    #pragma unroll
    for(int j=0;j<DD;j++) m[j] = __fmaf_rn(W0T[k*DD+j], xk, m[j]);
  }
  __half* hrow = hmir + (size_t)n*DD;
  #pragma unroll
  for(int j=0;j<DD;j++) hrow[j]=__float2half(fmaxf(m[j],0.f));
}

// ---------------- CSR build (r10 proven: rank-from-atomic, atomic-free scatter) ----
__global__ void k_deg(const int* __restrict__ dst, int* __restrict__ deg,
                      int* __restrict__ key){
  int e = blockIdx.x*blockDim.x + threadIdx.x;
  if(e < E_){
    int d = dst[e];
    int old = atomicAdd(&deg[d], 1);
    key[e] = d | (old << 18);     // d < 2^18, rank < 2^14
  }
}
__global__ void __launch_bounds__(1024) k_scanA(const int* __restrict__ deg,
                       int* __restrict__ incl, int* __restrict__ bsum){
  __shared__ int sh[1024];
  int g = blockIdx.x*1024 + threadIdx.x;
  int v = (g < N_) ? deg[g] : 0;
  sh[threadIdx.x]=v; __syncthreads();
  for(int o=1;o<1024;o<<=1){
    int a = (threadIdx.x>=o) ? sh[threadIdx.x-o] : 0;
    __syncthreads();
    sh[threadIdx.x]+=a;
    __syncthreads();
  }
  if(g < N_) incl[g]=sh[threadIdx.x];
  if(threadIdx.x==1023) bsum[blockIdx.x]=sh[1023];
}
__global__ void k_scanB(const int* __restrict__ bsum, int* __restrict__ boff){
  __shared__ int sh[256];
  int t=threadIdx.x;
  int v=(t<196)?bsum[t]:0;
  sh[t]=v; __syncthreads();
  for(int o=1;o<256;o<<=1){
    int a=(t>=o)?sh[t-o]:0; __syncthreads(); sh[t]+=a; __syncthreads();
  }
  if(t<196) boff[t]=sh[t]-v;   // exclusive
}
__global__ void __launch_bounds__(1024) k_scanC(const int* __restrict__ deg,
                       const int* __restrict__ boff, int* __restrict__ noff,
                       int* __restrict__ incl_cursor){
  int g = blockIdx.x*1024 + threadIdx.x;
  if(g >= N_) return;
  int ex = incl_cursor[g] - deg[g] + boff[g>>10];
  noff[g]=ex; incl_cursor[g]=ex;   // cursor = exclusive offset
}
// goff[g] = lower_bound(gid, g)  (gid sorted)
__global__ void k_goff(const int* __restrict__ gid, int* __restrict__ goff){
  int g = blockIdx.x*256 + threadIdx.x;
  if(g > B_) return;
  int lo=0, hi=N_;
  while(lo<hi){ int mid=(lo+hi)>>1; if(gid[mid]<g) lo=mid+1; else hi=mid; }
  goff[g]=lo;
}
// atomic-free scatter: position = noff[d] + precomputed rank
__global__ void k_scatter(const int* __restrict__ src, const int* __restrict__ key,
                          const int* __restrict__ noff, int* __restrict__ csr){
  int e = blockIdx.x*256 + threadIdx.x;
  int k = key[e];
  int d = k & 0x3FFFF;
  int p = noff[d] + (k >> 18);
  csr[p] = src[e];
}

// ---- fused step, MFMA edition --------------------------------------------------
// gather v3: 16 lanes per node x uint4 (16B = 8 halfs) -> 4 nodes per wave-phase,
// 4 phases (was 2 nodes x 8 phases x 8B). 2x outstanding bytes per wave, half the
// exposed-latency windows, 16B/lane coalescing sweet spot. Dim redistribution via
// wave-private LDS roundtrip (replaces shfl broadcast chain).
__global__ void __launch_bounds__(256) k_step(const float* __restrict__ Wall,
                       const __half* __restrict__ F16, const int* __restrict__ noff,
                       const int* __restrict__ deg, const int* __restrict__ csr,
                       const __half* __restrict__ curh, __half* __restrict__ nxth){
  __shared__ __align__(16) float  lds_acc[4][4][DD];
  __shared__ __align__(16) __half lds_m[4][16][40];
  const int t = threadIdx.x;
  const int w = t >> 6, l = t & 63;
  const int d = l & 31, half = l >> 5;
  const int ng = l >> 4;        // node subgroup 0..3
  const int L  = l & 15;
  const int q  = L >> 2;        // edge subgroup 0..3
  const int r4 = L & 3;         // dim octet: dims 8*r4 .. 8*r4+7
  const int n0 = blockIdx.x*64 + w*16;
  const float4* WmP = (const float4*)(Wall + OFF_WMT);
  const __half* rowbase = curh + 8*r4;   // per-lane fixed 16B dim offset
  // ---- phase 1: 4 phases x 4 nodes ----
  for(int p=0;p<4;p++){
    int n = n0 + 4*p + ng;
    int s0 = noff[n], len = deg[n];
    float a0=0.f,a1=0.f,a2=0.f,a3=0.f,a4=0.f,a5=0.f,a6=0.f,a7=0.f;
    for(int i=0; i<len; i+=32){
      int rem = len - i;                 // >= 1
      #pragma unroll
      for(int s=0;s<8;s++){
        int e  = 4*s + q;
        int ec = e < rem ? e : rem-1;    // clamp -> safe, cached line
        int idx = csr[s0 + i + ec];
        uint4 v = *(const uint4*)(rowbase + (size_t)idx*DD);
        if(e >= rem){ v.x=0u; v.y=0u; v.z=0u; v.w=0u; }
        float2 f0 = __half22float2(*(__half2*)&v.x);
        float2 f1 = __half22float2(*(__half2*)&v.y);
        float2 f2 = __half22float2(*(__half2*)&v.z);
        float2 f3 = __half22float2(*(__half2*)&v.w);
        a0 += f0.x; a1 += f0.y; a2 += f1.x; a3 += f1.y;
        a4 += f2.x; a5 += f2.y; a6 += f3.x; a7 += f3.y;
      }
    }
    // reduce over the 4 edge subgroups (bits 2,3 of L) within 16-lane groups
    #pragma unroll
    for(int off=4; off<=8; off<<=1){
      a0 += __shfl_xor(a0, off, 16); a1 += __shfl_xor(a1, off, 16);
      a2 += __shfl_xor(a2, off, 16); a3 += __shfl_xor(a3, off, 16);
      a4 += __shfl_xor(a4, off, 16); a5 += __shfl_xor(a5, off, 16);
      a6 += __shfl_xor(a6, off, 16); a7 += __shfl_xor(a7, off, 16);
    }
    if(q==0){
      float4* dstp = (float4*)&lds_acc[w][ng][8*r4];
      dstp[0] = make_float4(a0,a1,a2,a3);
      dstp[1] = make_float4(a4,a5,a6,a7);
    }
    // Wm matvec for this phase's 4 nodes (2 half-wave passes)
    #pragma unroll
    for(int rep=0;rep<2;rep++){
      int nn = 2*rep + half;
      const float4* ac = (const float4*)(&lds_acc[w][nn][0]);
      float m = 0.f;
      #pragma unroll
      for(int c=0;c<8;c++){
        float4 wv = WmP[c*32 + d];
        float4 av = ac[c];
        m = __fmaf_rn(wv.x, av.x, m);
        m = __fmaf_rn(wv.y, av.y, m);
        m = __fmaf_rn(wv.z, av.z, m);
        m = __fmaf_rn(wv.w, av.w, m);
      }
      lds_m[w][4*p + nn][d] = __float2half(fmaxf(m, 0.f));
    }
  }
  // ---- phase 2 (unchanged) ----
  const int rowa = l & 15, grp = l >> 4;
  f16x4 Am0 = *(const f16x4*)((const void*)&lds_m[w][rowa][4*grp]);
  f16x4 Am1 = *(const f16x4*)((const void*)&lds_m[w][rowa][16 + 4*grp]);
  const __half* hrow = curh + (size_t)(n0 + rowa)*DD;
  f16x4 Ah0 = *(const f16x4*)((const void*)(hrow + 4*grp));
  f16x4 Ah1 = *(const f16x4*)((const void*)(hrow + 16 + 4*grp));
  const f16x4* Bf = (const f16x4*)F16;
  f32x4 Drz[4], Din[2], Dhn[2];
  #pragma unroll
  for(int jt=0;jt<4;jt++){
    f32x4 a = {0.f,0.f,0.f,0.f};
    a = __builtin_amdgcn_mfma_f32_16x16x16f16(Ah0, Bf[(12 + jt*2    )*64 + l], a, 0,0,0);
    a = __builtin_amdgcn_mfma_f32_16x16x16f16(Ah1, Bf[(12 + jt*2 + 1)*64 + l], a, 0,0,0);
    a = __builtin_amdgcn_mfma_f32_16x16x16f16(Am0, Bf[(     jt*2    )*64 + l], a, 0,0,0);
    a = __builtin_amdgcn_mfma_f32_16x16x16f16(Am1, Bf[(     jt*2 + 1)*64 + l], a, 0,0,0);
    Drz[jt] = a;
  }
  #pragma unroll
  for(int s=0;s<2;s++){
    int jt = 4 + s;
    f32x4 a = {0.f,0.f,0.f,0.f};
    f32x4 b = {0.f,0.f,0.f,0.f};
    a = __builtin_amdgcn_mfma_f32_16x16x16f16(Am0, Bf[(     jt*2    )*64 + l], a, 0,0,0);
    a = __builtin_amdgcn_mfma_f32_16x16x16f16(Am1, Bf[(     jt*2 + 1)*64 + l], a, 0,0,0);
    b = __builtin_amdgcn_mfma_f32_16x16x16f16(Ah0, Bf[(12 + jt*2    )*64 + l], b, 0,0,0);
    b = __builtin_amdgcn_mfma_f32_16x16x16f16(Ah1, Bf[(12 + jt*2 + 1)*64 + l], b, 0,0,0);
    Din[s] = a; Dhn[s] = b;
  }
  #pragma unroll
  for(int s=0;s<2;s++){
    int dd = 16*s + rowa;
    float br = Wall[OFF_BIHG+dd]      + Wall[OFF_BHHG+dd];
    float bz = Wall[OFF_BIHG+DD+dd]   + Wall[OFF_BHHG+DD+dd];
    float bi = Wall[OFF_BIHG+2*DD+dd];
    float bh = Wall[OFF_BHHG+2*DD+dd];
    #pragma unroll
    for(int r=0;r<4;r++){
      int node = n0 + grp*4 + r;
      float hv = __half2float(curh[(size_t)node*DD + dd]);
      float rr = sigm(Drz[s][r]   + br);
      float zz = sigm(Drz[2+s][r] + bz);
      float nn = tanhfast((Din[s][r] + bi) + rr*(Dhn[s][r] + bh));
      nxth[(size_t)node*DD + dd] = __float2half((1.f - zz)*nn + zz*hv);
    }
  }
}

// ---- Set2Set + readout: block g owns graph g; 1024 thr = 16 waves (r7 win) -------
#define MAXEV 1024
__global__ void __launch_bounds__(1024, 8) k_s2s(const float* __restrict__ Wall,
                       const __half* __restrict__ hstate, const int* __restrict__ goff,
                       void* __restrict__ op, const int* __restrict__ flag){
  int g = blockIdx.x, t = threadIdx.x;
  int l32 = t & 31, g32 = t >> 5;        // 32 row-groups of 32 lanes
  __shared__ float evb[MAXEV];
  __shared__ float red[32*33];           // pass3 transpose-reduce, padded
  __shared__ float wred[16];
  __shared__ float qs[64];
  __shared__ float xb[64];
  __shared__ float hb[3][32];
  __shared__ float gbuf[128];
  __shared__ float yb[32];
  __shared__ float bc_mx, bc_inv;
  int s0 = goff[g], s1 = goff[g+1];
  int len = s1 - s0;
  int lc = len < MAXEV ? len : MAXEV;
  if(t < 64) qs[t] = 0.f;
  if(t < 96) hb[t>>5][t&31] = 0.f;
  float c0=0.f, c1=0.f, c2v=0.f;           // cell states on threads 0..31
  __syncthreads();
  for(int it=0; it<6; it++){
    if(t<64) xb[t]=qs[t];
    __syncthreads();
    // ---- LSTM layer 0 (xdim 64) ----
    if(t<128){
      const float* WT = Wall + OFF_WIH0T; const float* UT = Wall + OFF_WHH0T;
      float gv = Wall[OFF_BIH0+t] + Wall[OFF_BHH0+t];
      #pragma unroll 8
      for(int k=0;k<64;k++) gv = __fmaf_rn(WT[k*128+t], xb[k], gv);
      #pragma unroll 8
      for(int k=0;k<32;k++) gv = __fmaf_rn(UT[k*128+t], hb[0][k], gv);
      gbuf[t]=gv;
    }
    __syncthreads();
    if(t<32){
      float iv=sigm(gbuf[t]), fv=sigm(gbuf[32+t]), gg=tanhfast(gbuf[64+t]), ov=sigm(gbuf[96+t]);
      float c = fv*c0 + iv*gg; c0=c;
      float h2 = ov*tanhfast(c);
      hb[0][t]=h2; xb[t]=h2;
    }
    __syncthreads();
    // ---- LSTM layers 1,2 (xdim 32) ----
    for(int l=1;l<3;l++){
      if(t<128){
        const float* WT = Wall + (l==1?OFF_WIH1T:OFF_WIH2T);
        const float* UT = Wall + (l==1?OFF_WHH1T:OFF_WHH2T);
        int bo=(l-1)*128;
        float gv = Wall[OFF_BIH12+bo+t] + Wall[OFF_BHH12+bo+t];
        #pragma unroll 8
        for(int k=0;k<32;k++) gv = __fmaf_rn(WT[k*128+t], xb[k], gv);
        #pragma unroll 8
        for(int k=0;k<32;k++) gv = __fmaf_rn(UT[k*128+t], hb[l][k], gv);
        gbuf[t]=gv;
      }
      __syncthreads();
      if(t<32){
        float cp = (l==1)?c1:c2v;
        float iv=sigm(gbuf[t]), fv=sigm(gbuf[32+t]), gg=tanhfast(gbuf[64+t]), ov=sigm(gbuf[96+t]);
        float c = fv*cp + iv*gg;
        if(l==1) c1=c; else c2v=c;
        float h2 = ov*tanhfast(c);
        hb[l][t]=h2; xb[t]=h2;
      }
      __syncthreads();
    }
    float q = xb[l32];                     // layer-2 h, per-lane
    // ---- pass 1: logits + max ----
    float lmax = -INFINITY;
    for(int i=g32; i<len; i+=32){
      float v = __half2float(hstate[(size_t)(s0+i)*DD+l32])*q;
      #pragma unroll
      for(int o=16;o>0;o>>=1) v += __shfl_xor(v,o,32);
      if(i<lc && l32==0) evb[i]=v;
      lmax = fmaxf(lmax, v);
    }
    lmax = fmaxf(lmax, __shfl_xor(lmax, 32, 64));
    if((t&63)==0) wred[t>>6]=lmax;
    __syncthreads();
    if(t==0){ float m=wred[0];
      #pragma unroll
      for(int k=1;k<16;k++) m=fmaxf(m,wred[k]);
      bc_mx=m; }
    __syncthreads();
    float mx = bc_mx;
    // ---- pass 2: exp + sum; cache exp into evb ----
    float sm=0.f;
    for(int i=t;i<len;i+=1024){
      float v;
      if(i<lc) v=evb[i];
      else { v=0.f; for(int k=0;k<DD;k++) v += __half2float(hstate[(size_t)(s0+i)*DD+k])*xb[k]; }
      float e = __expf(v-mx);
      if(i<lc) evb[i]=e;
      sm += e;
    }
    #pragma unroll
    for(int o=32;o>0;o>>=1) sm += __shfl_xor(sm,o,64);
    if((t&63)==0) wred[t>>6]=sm;
    __syncthreads();
    if(t==0){ float s=0.f;
      #pragma unroll
      for(int k=0;k<16;k++) s+=wred[k];
      bc_inv = (s>0.f) ? 1.f/s : 0.f; }
    __syncthreads();
    float inv = bc_inv;
    // ---- pass 3: weighted sum ----
    float acc=0.f;
    for(int i=g32;i<len;i+=32){
      float fv = __half2float(hstate[(size_t)(s0+i)*DD+l32]);
      float wgt;
      if(i<lc) wgt=evb[i];
      else { float vv=fv*q;
             #pragma unroll
             for(int o=16;o>0;o>>=1) vv += __shfl_xor(vv,o,32);
             wgt=__expf(vv-mx); }
      acc = __fmaf_rn(wgt, fv, acc);
    }
    red[g32*33+l32]=acc; __syncthreads();
    if(t<32){
      float s=0.f;
      #pragma unroll
      for(int k=0;k<32;k++) s+=red[k*33+t];
      qs[32+t]=s*inv; qs[t]=xb[t];
    }
    __syncthreads();
  }
  // ---- readout MLP ----
  if(t<32){
    const float* W1 = Wall+OFF_WR1T;
    float s = Wall[OFF_BR1+t];
    #pragma unroll 8
    for(int k=0;k<64;k++) s = __fmaf_rn(W1[k*32+t], qs[k], s);
    yb[t]=fmaxf(s,0.f);
  }
  __syncthreads();
  if(t<32){
    const float* W2 = Wall+OFF_WR2T;
    float o = Wall[OFF_BR2+t];
    #pragma unroll 8
    for(int k=0;k<32;k++) o = __fmaf_rn(W2[k*32+t], yb[k], o);
    if(flag[0]) ((__hip_bfloat16*)op)[g*32+t]=__float2bfloat16(o);
    else        ((float*)op)[g*32+t]=o;
  }
}

extern "C" void kernel_launch(void* const* d_in, const int* in_sizes, int n_in,
                              void* d_out, int out_size, void* d_ws, size_t ws_size,
                              hipStream_t stream) {
  const int* nt  = (const int*)d_in[0];
  const int* src = (const int*)d_in[1];
  const int* dst = (const int*)d_in[2];
  const int* gid = (const int*)d_in[3];
  float* W = (float*)d_ws;
  char* base = (char*)d_ws;
  __half* F16 = (__half*)(base + F16_BYTE);
  __half* h0 = (__half*)(base + H0_BYTE);
  __half* h1 = (__half*)(base + H1_BYTE);
  int* I = (int*)(base + INT_BASE);
  int* deg=I+I_DEG; int* noff=I+I_NOFF; int* cursor=I+I_CURSOR;
  int* goff=I+I_GOFF; int* bsum=I+I_BSUM; int* boff=I+I_BOFF; int* csr=I+I_CSR;
  int* flag=I+I_FLAG;
  // edge-rank key temp reuses h1 (E ints = 12.8 MB); h1 is first written by
  // k_step step 0, strictly after scatter completes. k_deg rewrites every launch.
  int* key = (int*)h1;

  hipMemsetAsync(deg, 0, (size_t)N_*4, stream);

  k_detect<<<1,64,0,stream>>>((const unsigned int*)d_in[4], flag);

  PrepArgs pa;
  const int sidx[22]={4,6,10,11,14,15,18,19,21,23, 5,7,8,9,12,13,16,16,17,17,20,22};
  const int offs[22]={OFF_EMB,OFF_B0,OFF_BIHG,OFF_BHHG,OFF_BIH0,OFF_BHH0,OFF_BIH12,
                      OFF_BHH12,OFF_BR1,OFF_BR2, OFF_W0T,OFF_WMT,OFF_WIHGT,OFF_WHHGT,
                      OFF_WIH0T,OFF_WHH0T,OFF_WIH1T,OFF_WIH2T,OFF_WHH1T,OFF_WHH2T,
                      OFF_WR1T,OFF_WR2T};
  const int szs[22]={3232,32,96,96,128,128,256,256,32,32, 1024,1024,3072,3072,
                     8192,4096,4096,4096,4096,4096,2048,1024};
  // Wm chunk-packed fp32 (float4 matvec); Wih_g/Whh_g plain [96][32] (k_prep16 source)
  const int trR[22]={0,0,0,0,0,0,0,0,0,0, 32,0,0,0,128,128,128,128,128,128,32,32};
  const int pkv[22]={0,0,0,0,0,0,0,0,0,0, 0,32,0,0,0,0,0,0,0,0,0,0};
  const int sof[22]={0,0,0,0,0,0,0,0,0,0, 0,0,0,0,0,0,0,4096,0,4096,0,0};
  for(int i=0;i<22;i++){ pa.s[i]=d_in[sidx[i]]; pa.off[i]=offs[i]; pa.sz[i]=szs[i];
                         pa.trR[i]=trR[i]; pa.soff[i]=sof[i]; pa.pk[i]=pkv[i]; }
  hipLaunchKernelGGL(k_prep, dim3(32,22), dim3(256), 0, stream, pa, W, flag);
  k_prep16<<<24,256,0,stream>>>(W, F16);

  k_lin0<<<782,256,0,stream>>>(nt, W, h0);
  k_deg<<<12500,256,0,stream>>>(dst, deg, key);
  k_scanA<<<196,1024,0,stream>>>(deg, cursor, bsum);
  k_scanB<<<1,256,0,stream>>>(bsum, boff);
  k_scanC<<<196,1024,0,stream>>>(deg, boff, noff, cursor);
  k_goff<<<3,256,0,stream>>>(gid, goff);
  k_scatter<<<12500,256,0,stream>>>(src, key, noff, csr);

  // 6 MP steps on fp16 double-buffered state (even count -> final state in h0)
  __half* curh = h0; __half* nxth = h1;
  for(int s=0;s<6;s++){
    k_step<<<3125,256,0,stream>>>(W, F16, noff, deg, csr, curh, nxth);
    __half* tmp = curh; curh = nxth; nxth = tmp;
  }
  // whole Set2Set + readout in one launch (block g == graph g, fully independent)
  k_s2s<<<B_,1024,0,stream>>>(W, curh, goff, d_out, flag);
}

// Round 14
// 854.015 us; speedup vs baseline: 1.2485x; 1.2485x over previous
//
#include <hip/hip_runtime.h>
#include <hip/hip_bf16.h>
#include <hip/hip_fp16.h>

#define DD 32
constexpr int N_ = 200000;
constexpr int E_ = 3200000;
constexpr int B_ = 512;
constexpr int IDXCAP = 768;   // per-wave staged edge-index capacity (avg 256, +32 sigma)

typedef _Float16 f16x4 __attribute__((ext_vector_type(4)));
typedef float f32x4 __attribute__((ext_vector_type(4)));

// ---------------- workspace layout ----------------
constexpr int OFF_EMB=0, OFF_B0=3232, OFF_BIHG=3264, OFF_BHHG=3360, OFF_BIH0=3456,
  OFF_BHH0=3584, OFF_BIH12=3712, OFF_BHH12=3968, OFF_BR1=4224, OFF_BR2=4256,
  OFF_W0T=4288, OFF_WMT=5312, OFF_WIHGT=6336, OFF_WHHGT=9408,
  OFF_WIH0T=12480, OFF_WHH0T=20672, OFF_WIH1T=24768, OFF_WHH1T=28864,
  OFF_WIH2T=32960, OFF_WHH2T=37056, OFF_WR1T=41152, OFF_WR2T=43200;
constexpr long FLOAT_END=44288L;
// fp16 MFMA weight-fragment region (6144 halfs = 12288 B), then fp16 states
constexpr size_t F16_BYTE = (size_t)FLOAT_END*4;           // 177152
constexpr size_t H0_BYTE  = F16_BYTE + 12288;              // 189440
constexpr size_t H1_BYTE  = H0_BYTE + (size_t)N_*DD*2;     // fp16 state B
constexpr size_t INT_BASE = H1_BYTE + (size_t)N_*DD*2;     // 25789440, 256B aligned
// int offsets (in ints, from INT_BASE)
constexpr int I_DEG=0, I_NOFF=200512, I_CURSOR=400512, I_GOFF=600512,
  I_BSUM=601088, I_BOFF=601344, I_CSR=601600;      // csr: E ints
constexpr int I_FLAG=3801600;

__device__ __forceinline__ float bf2f(unsigned short u){ return __uint_as_float(((unsigned)u)<<16); }
__device__ __forceinline__ float sigm(float x){ return 1.0f/(1.0f+__expf(-x)); }
__device__ __forceinline__ float tanhfast(float x){ return 1.0f - 2.0f/(__expf(2.0f*x)+1.0f); }

// ---------------- input-dtype detection ----------------
__global__ void k_detect(const unsigned int* __restrict__ emb_raw, int* __restrict__ flag){
  if(threadIdx.x==0){
    unsigned v=0;
    for(int i=16;i<32;i++) v |= emb_raw[i];
    flag[0] = v ? 1 : 0;   // 1 = bf16 inputs, 0 = f32 inputs
  }
}

// -------- weight prep: (bf16|f32) -> fp32 ------------------------------------------
struct PrepArgs { const void* s[22]; int off[22]; int sz[22]; int trR[22]; int soff[22]; int pk[22]; };

__global__ void k_prep(PrepArgs a, float* __restrict__ W, const int* __restrict__ flag){
  int bf = flag[0];
  int seg = blockIdx.y;
  int i = blockIdx.x*256 + threadIdx.x;
  if(i >= a.sz[seg]) return;
  int R = a.trR[seg];
  int P = a.pk[seg];
  int sidx;
  if(P){
    int c = i/(4*P); int rem = i%(4*P); int col = rem>>2; int s = rem&3;
    sidx = col*DD + 4*c + s;
  } else if(R){ int C = a.sz[seg]/R; sidx = (i%R)*C + (i/R); } else sidx = i;
  sidx += a.soff[seg];
  float v = bf ? bf2f(((const unsigned short*)a.s[seg])[sidx])
               : ((const float*)a.s[seg])[sidx];
  W[a.off[seg]+i] = v;
}

// ---- pack GRU gate weights into fp16 MFMA B-fragments (16x16x16f16 layout) ----
__global__ void k_prep16(const float* __restrict__ Wall, __half* __restrict__ F){
  int id = blockIdx.x*256 + threadIdx.x;
  if(id >= 6144) return;
  int e  = id & 3;
  int l  = (id >> 2) & 63;
  int kh = (id >> 8) & 1;
  int tmp = id >> 9;
  int jt  = tmp % 6;
  int reg = tmp / 6;
  int j = 16*jt + (l & 15);
  int k = 16*kh + 4*(l >> 4) + e;
  int srcoff = (reg==0 ? OFF_WIHGT : OFF_WHHGT) + j*DD + k;
  F[id] = __float2half(Wall[srcoff]);
}

// ---------------- lin0: h0[n] = fp16(relu(W0 @ emb[node_type[n]] + b0)) -----------
__global__ void k_lin0(const int* __restrict__ nt, const float* __restrict__ Wall,
                       __half* __restrict__ hmir){
  int n = blockIdx.x*blockDim.x + threadIdx.x;
  if(n >= N_) return;
  const float* er  = Wall + OFF_EMB + nt[n]*DD;
  const float* W0T = Wall + OFF_W0T;
  const float* b0  = Wall + OFF_B0;
  float m[DD];
  #pragma unroll
  for(int j=0;j<DD;j++) m[j]=b0[j];
  #pragma unroll 4
  for(int k=0;k<DD;k++){
    float xk = er[k];
    #pragma unroll
    for(int j=0;j<DD;j++) m[j] = __fmaf_rn(W0T[k*DD+j], xk, m[j]);
  }
  __half* hrow = hmir + (size_t)n*DD;
  #pragma unroll
  for(int j=0;j<DD;j++) hrow[j]=__float2half(fmaxf(m[j],0.f));
}

// ---------------- CSR build (r10 proven: rank-from-atomic, atomic-free scatter) ----
__global__ void k_deg(const int* __restrict__ dst, int* __restrict__ deg,
                      int* __restrict__ key){
  int e = blockIdx.x*blockDim.x + threadIdx.x;
  if(e < E_){
    int d = dst[e];
    int old = atomicAdd(&deg[d], 1);
    key[e] = d | (old << 18);     // d < 2^18, rank < 2^14
  }
}
__global__ void __launch_bounds__(1024) k_scanA(const int* __restrict__ deg,
                       int* __restrict__ incl, int* __restrict__ bsum){
  __shared__ int sh[1024];
  int g = blockIdx.x*1024 + threadIdx.x;
  int v = (g < N_) ? deg[g] : 0;
  sh[threadIdx.x]=v; __syncthreads();
  for(int o=1;o<1024;o<<=1){
    int a = (threadIdx.x>=o) ? sh[threadIdx.x-o] : 0;
    __syncthreads();
    sh[threadIdx.x]+=a;
    __syncthreads();
  }
  if(g < N_) incl[g]=sh[threadIdx.x];
  if(threadIdx.x==1023) bsum[blockIdx.x]=sh[1023];
}
__global__ void k_scanB(const int* __restrict__ bsum, int* __restrict__ boff){
  __shared__ int sh[256];
  int t=threadIdx.x;
  int v=(t<196)?bsum[t]:0;
  sh[t]=v; __syncthreads();
  for(int o=1;o<256;o<<=1){
    int a=(t>=o)?sh[t-o]:0; __syncthreads(); sh[t]+=a; __syncthreads();
  }
  if(t<196) boff[t]=sh[t]-v;   // exclusive
}
__global__ void __launch_bounds__(1024) k_scanC(const int* __restrict__ deg,
                       const int* __restrict__ boff, int* __restrict__ noff,
                       int* __restrict__ incl_cursor){
  int g = blockIdx.x*1024 + threadIdx.x;
  if(g >= N_) return;
  int ex = incl_cursor[g] - deg[g] + boff[g>>10];
  noff[g]=ex; incl_cursor[g]=ex;   // cursor = exclusive offset
}
// goff[g] = lower_bound(gid, g)  (gid sorted)
__global__ void k_goff(const int* __restrict__ gid, int* __restrict__ goff){
  int g = blockIdx.x*256 + threadIdx.x;
  if(g > B_) return;
  int lo=0, hi=N_;
  while(lo<hi){ int mid=(lo+hi)>>1; if(gid[mid]<g) lo=mid+1; else hi=mid; }
  goff[g]=lo;
}
// atomic-free scatter: position = noff[d] + precomputed rank
__global__ void k_scatter(const int* __restrict__ src, const int* __restrict__ key,
                          const int* __restrict__ noff, int* __restrict__ csr){
  int e = blockIdx.x*256 + threadIdx.x;
  int k = key[e];
  int d = k & 0x3FFFF;
  int p = noff[d] + (k >> 18);
  csr[p] = src[e];
}

// ---- fused step, MFMA edition --------------------------------------------------
// gather v4 = r10's v2 + LDS index staging: a wave's 16 nodes have CONTIGUOUS edge
// lists in csr, so the wave bulk-loads its whole index range (coalesced, one latency
// window) and preloads noff/deg (one window). Per-phase dependent chain collapses
// from csr->row to row only. Fallback to direct csr if range > IDXCAP (P ~ 0).
__global__ void __launch_bounds__(256) k_step(const float* __restrict__ Wall,
                       const __half* __restrict__ F16, const int* __restrict__ noff,
                       const int* __restrict__ deg, const int* __restrict__ csr,
                       const __half* __restrict__ curh, __half* __restrict__ nxth){
  __shared__ __align__(16) float  lds_acc[4][2][DD];
  __shared__ __align__(16) __half lds_m[4][16][40];
  __shared__ int lds_idx[4][IDXCAP];
  __shared__ int lds_nd[4][32];          // [0..15]=noff, [16..31]=deg
  const int t = threadIdx.x;
  const int w = t >> 6, l = t & 63;
  const int d = l & 31, half = l >> 5;
  const int q  = d >> 3;        // edge subgroup 0..3
  const int r8 = d & 7;         // dim-quad index: dims 4*r8 .. 4*r8+3
  const int n0 = blockIdx.x*64 + w*16;
  const float4* WmP = (const float4*)(Wall + OFF_WMT);
  const __half* rowbase = curh + 4*r8;   // per-lane fixed dim offset
  // ---- stage node meta + edge indices (wave-private; in-order DS pipe) ----
  if(l < 16){
    lds_nd[w][l]    = noff[n0+l];
    lds_nd[w][16+l] = deg[n0+l];
  }
  int s_begin = lds_nd[w][0];
  int total   = lds_nd[w][15] + lds_nd[w][31] - s_begin;
  int tc = total < IDXCAP ? total : IDXCAP;
  for(int i=l; i<tc; i+=64) lds_idx[w][i] = csr[s_begin+i];
  // ---- phase 1 ----
  for(int p=0;p<8;p++){
    int ni = 2*p + half;
    int s0 = lds_nd[w][ni] - s_begin;
    int len = lds_nd[w][16+ni];
    float a0=0.f, a1=0.f, a2=0.f, a3=0.f;
    if(s0 + len <= IDXCAP){
      const int* ip = &lds_idx[w][s0];
      for(int i=0; i<len; i+=32){
        int rem = len - i;                 // >= 1
        #pragma unroll
        for(int s=0;s<8;s++){
          int e  = 4*s + q;
          int ec = e < rem ? e : rem-1;    // clamp -> safe
          int idx = ip[i + ec];
          uint2 v = *(const uint2*)(rowbase + (size_t)idx*DD);
          if(e >= rem){ v.x = 0u; v.y = 0u; }
          float2 f0 = __half22float2(*(__half2*)&v.x);
          float2 f1 = __half22float2(*(__half2*)&v.y);
          a0 += f0.x; a1 += f0.y; a2 += f1.x; a3 += f1.y;
        }
      }
    } else {                               // cold fallback (range > IDXCAP)
      for(int i=0; i<len; i+=32){
        int rem = len - i;
        #pragma unroll
        for(int s=0;s<8;s++){
          int e  = 4*s + q;
          int ec = e < rem ? e : rem-1;
          int idx = csr[s_begin + s0 + i + ec];
          uint2 v = *(const uint2*)(rowbase + (size_t)idx*DD);
          if(e >= rem){ v.x = 0u; v.y = 0u; }
          float2 f0 = __half22float2(*(__half2*)&v.x);
          float2 f1 = __half22float2(*(__half2*)&v.y);
          a0 += f0.x; a1 += f0.y; a2 += f1.x; a3 += f1.y;
        }
      }
    }
    #pragma unroll
    for(int off=8; off<=16; off<<=1){
      a0 += __shfl_xor(a0, off, 32);
      a1 += __shfl_xor(a1, off, 32);
      a2 += __shfl_xor(a2, off, 32);
      a3 += __shfl_xor(a3, off, 32);
    }
    float v0 = __shfl(a0, d>>2, 32);
    float v1 = __shfl(a1, d>>2, 32);
    float v2 = __shfl(a2, d>>2, 32);
    float v3 = __shfl(a3, d>>2, 32);
    float accd = (d&1) ? ((d&2)? v3 : v1) : ((d&2)? v2 : v0);
    lds_acc[w][half][d] = accd;
    const float4* ac = (const float4*)(&lds_acc[w][half][0]);
    float m = 0.f;
    #pragma unroll
    for(int c=0;c<8;c++){
      float4 wv = WmP[c*32 + d];
      float4 av = ac[c];
      m = __fmaf_rn(wv.x, av.x, m);
      m = __fmaf_rn(wv.y, av.y, m);
      m = __fmaf_rn(wv.z, av.z, m);
      m = __fmaf_rn(wv.w, av.w, m);
    }
    lds_m[w][2*p+half][d] = __float2half(fmaxf(m, 0.f));
  }
  // ---- phase 2 ----
  const int rowa = l & 15, grp = l >> 4;
  f16x4 Am0 = *(const f16x4*)((const void*)&lds_m[w][rowa][4*grp]);
  f16x4 Am1 = *(const f16x4*)((const void*)&lds_m[w][rowa][16 + 4*grp]);
  const __half* hrow = curh + (size_t)(n0 + rowa)*DD;
  f16x4 Ah0 = *(const f16x4*)((const void*)(hrow + 4*grp));
  f16x4 Ah1 = *(const f16x4*)((const void*)(hrow + 16 + 4*grp));
  const f16x4* Bf = (const f16x4*)F16;
  f32x4 Drz[4], Din[2], Dhn[2];
  #pragma unroll
  for(int jt=0;jt<4;jt++){
    f32x4 a = {0.f,0.f,0.f,0.f};
    a = __builtin_amdgcn_mfma_f32_16x16x16f16(Ah0, Bf[(12 + jt*2    )*64 + l], a, 0,0,0);
    a = __builtin_amdgcn_mfma_f32_16x16x16f16(Ah1, Bf[(12 + jt*2 + 1)*64 + l], a, 0,0,0);
    a = __builtin_amdgcn_mfma_f32_16x16x16f16(Am0, Bf[(     jt*2    )*64 + l], a, 0,0,0);
    a = __builtin_amdgcn_mfma_f32_16x16x16f16(Am1, Bf[(     jt*2 + 1)*64 + l], a, 0,0,0);
    Drz[jt] = a;
  }
  #pragma unroll
  for(int s=0;s<2;s++){
    int jt = 4 + s;
    f32x4 a = {0.f,0.f,0.f,0.f};
    f32x4 b = {0.f,0.f,0.f,0.f};
    a = __builtin_amdgcn_mfma_f32_16x16x16f16(Am0, Bf[(     jt*2    )*64 + l], a, 0,0,0);
    a = __builtin_amdgcn_mfma_f32_16x16x16f16(Am1, Bf[(     jt*2 + 1)*64 + l], a, 0,0,0);
    b = __builtin_amdgcn_mfma_f32_16x16x16f16(Ah0, Bf[(12 + jt*2    )*64 + l], b, 0,0,0);
    b = __builtin_amdgcn_mfma_f32_16x16x16f16(Ah1, Bf[(12 + jt*2 + 1)*64 + l], b, 0,0,0);
    Din[s] = a; Dhn[s] = b;
  }
  #pragma unroll
  for(int s=0;s<2;s++){
    int dd = 16*s + rowa;
    float br = Wall[OFF_BIHG+dd]      + Wall[OFF_BHHG+dd];
    float bz = Wall[OFF_BIHG+DD+dd]   + Wall[OFF_BHHG+DD+dd];
    float bi = Wall[OFF_BIHG+2*DD+dd];
    float bh = Wall[OFF_BHHG+2*DD+dd];
    #pragma unroll
    for(int r=0;r<4;r++){
      int node = n0 + grp*4 + r;
      float hv = __half2float(curh[(size_t)node*DD + dd]);
      float rr = sigm(Drz[s][r]   + br);
      float zz = sigm(Drz[2+s][r] + bz);
      float nn = tanhfast((Din[s][r] + bi) + rr*(Dhn[s][r] + bh));
      nxth[(size_t)node*DD + dd] = __float2half((1.f - zz)*nn + zz*hv);
    }
  }
}

// ---- Set2Set + readout: block g owns graph g; 1024 thr = 16 waves (r7 win) -------
#define MAXEV 1024
__global__ void __launch_bounds__(1024, 8) k_s2s(const float* __restrict__ Wall,
                       const __half* __restrict__ hstate, const int* __restrict__ goff,
                       void* __restrict__ op, const int* __restrict__ flag){
  int g = blockIdx.x, t = threadIdx.x;
  int l32 = t & 31, g32 = t >> 5;        // 32 row-groups of 32 lanes
  __shared__ float evb[MAXEV];
  __shared__ float red[32*33];           // pass3 transpose-reduce, padded
  __shared__ float wred[16];
  __shared__ float qs[64];
  __shared__ float xb[64];
  __shared__ float hb[3][32];
  __shared__ float gbuf[128];
  __shared__ float yb[32];
  __shared__ float bc_mx, bc_inv;
  int s0 = goff[g], s1 = goff[g+1];
  int len = s1 - s0;
  int lc = len < MAXEV ? len : MAXEV;
  if(t < 64) qs[t] = 0.f;
  if(t < 96) hb[t>>5][t&31] = 0.f;
  float c0=0.f, c1=0.f, c2v=0.f;           // cell states on threads 0..31
  __syncthreads();
  for(int it=0; it<6; it++){
    if(t<64) xb[t]=qs[t];
    __syncthreads();
    // ---- LSTM layer 0 (xdim 64) ----
    if(t<128){
      const float* WT = Wall + OFF_WIH0T; const float* UT = Wall + OFF_WHH0T;
      float gv = Wall[OFF_BIH0+t] + Wall[OFF_BHH0+t];
      #pragma unroll 8
      for(int k=0;k<64;k++) gv = __fmaf_rn(WT[k*128+t], xb[k], gv);
      #pragma unroll 8
      for(int k=0;k<32;k++) gv = __fmaf_rn(UT[k*128+t], hb[0][k], gv);
      gbuf[t]=gv;
    }
    __syncthreads();
    if(t<32){
      float iv=sigm(gbuf[t]), fv=sigm(gbuf[32+t]), gg=tanhfast(gbuf[64+t]), ov=sigm(gbuf[96+t]);
      float c = fv*c0 + iv*gg; c0=c;
      float h2 = ov*tanhfast(c);
      hb[0][t]=h2; xb[t]=h2;
    }
    __syncthreads();
    // ---- LSTM layers 1,2 (xdim 32) ----
    for(int l=1;l<3;l++){
      if(t<128){
        const float* WT = Wall + (l==1?OFF_WIH1T:OFF_WIH2T);
        const float* UT = Wall + (l==1?OFF_WHH1T:OFF_WHH2T);
        int bo=(l-1)*128;
        float gv = Wall[OFF_BIH12+bo+t] + Wall[OFF_BHH12+bo+t];
        #pragma unroll 8
        for(int k=0;k<32;k++) gv = __fmaf_rn(WT[k*128+t], xb[k], gv);
        #pragma unroll 8
        for(int k=0;k<32;k++) gv = __fmaf_rn(UT[k*128+t], hb[l][k], gv);
        gbuf[t]=gv;
      }
      __syncthreads();
      if(t<32){
        float cp = (l==1)?c1:c2v;
        float iv=sigm(gbuf[t]), fv=sigm(gbuf[32+t]), gg=tanhfast(gbuf[64+t]), ov=sigm(gbuf[96+t]);
        float c = fv*cp + iv*gg;
        if(l==1) c1=c; else c2v=c;
        float h2 = ov*tanhfast(c);
        hb[l][t]=h2; xb[t]=h2;
      }
      __syncthreads();
    }
    float q = xb[l32];                     // layer-2 h, per-lane
    // ---- pass 1: logits + max ----
    float lmax = -INFINITY;
    for(int i=g32; i<len; i+=32){
      float v = __half2float(hstate[(size_t)(s0+i)*DD+l32])*q;
      #pragma unroll
      for(int o=16;o>0;o>>=1) v += __shfl_xor(v,o,32);
      if(i<lc && l32==0) evb[i]=v;
      lmax = fmaxf(lmax, v);
    }
    lmax = fmaxf(lmax, __shfl_xor(lmax, 32, 64));
    if((t&63)==0) wred[t>>6]=lmax;
    __syncthreads();
    if(t==0){ float m=wred[0];
      #pragma unroll
      for(int k=1;k<16;k++) m=fmaxf(m,wred[k]);
      bc_mx=m; }
    __syncthreads();
    float mx = bc_mx;
    // ---- pass 2: exp + sum; cache exp into evb ----
    float sm=0.f;
    for(int i=t;i<len;i+=1024){
      float v;
      if(i<lc) v=evb[i];
      else { v=0.f; for(int k=0;k<DD;k++) v += __half2float(hstate[(size_t)(s0+i)*DD+k])*xb[k]; }
      float e = __expf(v-mx);
      if(i<lc) evb[i]=e;
      sm += e;
    }
    #pragma unroll
    for(int o=32;o>0;o>>=1) sm += __shfl_xor(sm,o,64);
    if((t&63)==0) wred[t>>6]=sm;
    __syncthreads();
    if(t==0){ float s=0.f;
      #pragma unroll
      for(int k=0;k<16;k++) s+=wred[k];
      bc_inv = (s>0.f) ? 1.f/s : 0.f; }
    __syncthreads();
    float inv = bc_inv;
    // ---- pass 3: weighted sum ----
    float acc=0.f;
    for(int i=g32;i<len;i+=32){
      float fv = __half2float(hstate[(size_t)(s0+i)*DD+l32]);
      float wgt;
      if(i<lc) wgt=evb[i];
      else { float vv=fv*q;
             #pragma unroll
             for(int o=16;o>0;o>>=1) vv += __shfl_xor(vv,o,32);
             wgt=__expf(vv-mx); }
      acc = __fmaf_rn(wgt, fv, acc);
    }
    red[g32*33+l32]=acc; __syncthreads();
    if(t<32){
      float s=0.f;
      #pragma unroll
      for(int k=0;k<32;k++) s+=red[k*33+t];
      qs[32+t]=s*inv; qs[t]=xb[t];
    }
    __syncthreads();
  }
  // ---- readout MLP ----
  if(t<32){
    const float* W1 = Wall+OFF_WR1T;
    float s = Wall[OFF_BR1+t];
    #pragma unroll 8
    for(int k=0;k<64;k++) s = __fmaf_rn(W1[k*32+t], qs[k], s);
    yb[t]=fmaxf(s,0.f);
  }
  __syncthreads();
  if(t<32){
    const float* W2 = Wall+OFF_WR2T;
    float o = Wall[OFF_BR2+t];
    #pragma unroll 8
    for(int k=0;k<32;k++) o = __fmaf_rn(W2[k*32+t], yb[k], o);
    if(flag[0]) ((__hip_bfloat16*)op)[g*32+t]=__float2bfloat16(o);
    else        ((float*)op)[g*32+t]=o;
  }
}

extern "C" void kernel_launch(void* const* d_in, const int* in_sizes, int n_in,
                              void* d_out, int out_size, void* d_ws, size_t ws_size,
                              hipStream_t stream) {
  const int* nt  = (const int*)d_in[0];
  const int* src = (const int*)d_in[1];
  const int* dst = (const int*)d_in[2];
  const int* gid = (const int*)d_in[3];
  float* W = (float*)d_ws;
  char* base = (char*)d_ws;
  __half* F16 = (__half*)(base + F16_BYTE);
  __half* h0 = (__half*)(base + H0_BYTE);
  __half* h1 = (__half*)(base + H1_BYTE);
  int* I = (int*)(base + INT_BASE);
  int* deg=I+I_DEG; int* noff=I+I_NOFF; int* cursor=I+I_CURSOR;
  int* goff=I+I_GOFF; int* bsum=I+I_BSUM; int* boff=I+I_BOFF; int* csr=I+I_CSR;
  int* flag=I+I_FLAG;
  // edge-rank key temp reuses h1 (E ints = 12.8 MB); h1 is first written by
  // k_step step 0, strictly after scatter completes. k_deg rewrites every launch.
  int* key = (int*)h1;

  hipMemsetAsync(deg, 0, (size_t)N_*4, stream);

  k_detect<<<1,64,0,stream>>>((const unsigned int*)d_in[4], flag);

  PrepArgs pa;
  const int sidx[22]={4,6,10,11,14,15,18,19,21,23, 5,7,8,9,12,13,16,16,17,17,20,22};
  const int offs[22]={OFF_EMB,OFF_B0,OFF_BIHG,OFF_BHHG,OFF_BIH0,OFF_BHH0,OFF_BIH12,
                      OFF_BHH12,OFF_BR1,OFF_BR2, OFF_W0T,OFF_WMT,OFF_WIHGT,OFF_WHHGT,
                      OFF_WIH0T,OFF_WHH0T,OFF_WIH1T,OFF_WIH2T,OFF_WHH1T,OFF_WHH2T,
                      OFF_WR1T,OFF_WR2T};
  const int szs[22]={3232,32,96,96,128,128,256,256,32,32, 1024,1024,3072,3072,
                     8192,4096,4096,4096,4096,4096,2048,1024};
  // Wm chunk-packed fp32 (float4 matvec); Wih_g/Whh_g plain [96][32] (k_prep16 source)
  const int trR[22]={0,0,0,0,0,0,0,0,0,0, 32,0,0,0,128,128,128,128,128,128,32,32};
  const int pkv[22]={0,0,0,0,0,0,0,0,0,0, 0,32,0,0,0,0,0,0,0,0,0,0};
  const int sof[22]={0,0,0,0,0,0,0,0,0,0, 0,0,0,0,0,0,0,4096,0,4096,0,0};
  for(int i=0;i<22;i++){ pa.s[i]=d_in[sidx[i]]; pa.off[i]=offs[i]; pa.sz[i]=szs[i];
                         pa.trR[i]=trR[i]; pa.soff[i]=sof[i]; pa.pk[i]=pkv[i]; }
  hipLaunchKernelGGL(k_prep, dim3(32,22), dim3(256), 0, stream, pa, W, flag);
  k_prep16<<<24,256,0,stream>>>(W, F16);

  k_lin0<<<782,256,0,stream>>>(nt, W, h0);
  k_deg<<<12500,256,0,stream>>>(dst, deg, key);
  k_scanA<<<196,1024,0,stream>>>(deg, cursor, bsum);
  k_scanB<<<1,256,0,stream>>>(bsum, boff);
  k_scanC<<<196,1024,0,stream>>>(deg, boff, noff, cursor);
  k_goff<<<3,256,0,stream>>>(gid, goff);
  k_scatter<<<12500,256,0,stream>>>(src, key, noff, csr);

  // 6 MP steps on fp16 double-buffered state (even count -> final state in h0)
  __half* curh = h0; __half* nxth = h1;
  for(int s=0;s<6;s++){
    k_step<<<3125,256,0,stream>>>(W, F16, noff, deg, csr, curh, nxth);
    __half* tmp = curh; curh = nxth; nxth = tmp;
  }
  // whole Set2Set + readout in one launch (block g == graph g, fully independent)
  k_s2s<<<B_,1024,0,stream>>>(W, curh, goff, d_out, flag);
}

// Round 15
// 800.293 us; speedup vs baseline: 1.3323x; 1.0671x over previous
//
#include <hip/hip_runtime.h>
#include <hip/hip_bf16.h>
#include <hip/hip_fp16.h>

#define DD 32
constexpr int N_ = 200000;
constexpr int E_ = 3200000;
constexpr int B_ = 512;
constexpr int IDXCAP = 768;   // per-wave staged edge-index capacity (avg 256, +32 sigma)

typedef _Float16 f16x4 __attribute__((ext_vector_type(4)));
typedef float f32x4 __attribute__((ext_vector_type(4)));

// ---------------- workspace layout ----------------
constexpr int OFF_EMB=0, OFF_B0=3232, OFF_BIHG=3264, OFF_BHHG=3360, OFF_BIH0=3456,
  OFF_BHH0=3584, OFF_BIH12=3712, OFF_BHH12=3968, OFF_BR1=4224, OFF_BR2=4256,
  OFF_W0T=4288, OFF_WMT=5312, OFF_WIHGT=6336, OFF_WHHGT=9408,
  OFF_WIH0T=12480, OFF_WHH0T=20672, OFF_WIH1T=24768, OFF_WHH1T=28864,
  OFF_WIH2T=32960, OFF_WHH2T=37056, OFF_WR1T=41152, OFF_WR2T=43200;
constexpr long FLOAT_END=44288L;
// fp16 MFMA weight-fragment region (6144 halfs = 12288 B), then fp16 states
constexpr size_t F16_BYTE = (size_t)FLOAT_END*4;           // 177152
constexpr size_t H0_BYTE  = F16_BYTE + 12288;              // 189440
constexpr size_t H1_BYTE  = H0_BYTE + (size_t)N_*DD*2;     // fp16 state B
constexpr size_t INT_BASE = H1_BYTE + (size_t)N_*DD*2;     // 25789440, 256B aligned
// int offsets (in ints, from INT_BASE)
constexpr int I_DEG=0, I_NOFF=200512, I_CURSOR=400512, I_GOFF=600512,
  I_BSUM=601088, I_BOFF=601344, I_CSR=601600;      // csr: E ints
constexpr int I_FLAG=3801600;

__device__ __forceinline__ float bf2f(unsigned short u){ return __uint_as_float(((unsigned)u)<<16); }
__device__ __forceinline__ float sigm(float x){ return 1.0f/(1.0f+__expf(-x)); }
__device__ __forceinline__ float tanhfast(float x){ return 1.0f - 2.0f/(__expf(2.0f*x)+1.0f); }

// one 8-slot predicated gather batch (32 edges across 4 lane-subgroups)
__device__ __forceinline__ void gbatch(const int* __restrict__ ip, int i, int rem,
                                       const __half* __restrict__ rowbase, int q,
                                       float& a0, float& a1, float& a2, float& a3){
  #pragma unroll
  for(int s=0;s<8;s++){
    int e  = 4*s + q;
    int ec = e < rem ? e : rem-1;
    int idx = ip[i + ec];
    uint2 v = *(const uint2*)(rowbase + (size_t)idx*DD);
    if(e >= rem){ v.x = 0u; v.y = 0u; }
    float2 f0 = __half22float2(*(__half2*)&v.x);
    float2 f1 = __half22float2(*(__half2*)&v.y);
    a0 += f0.x; a1 += f0.y; a2 += f1.x; a3 += f1.y;
  }
}

// ---------------- input-dtype detection ----------------
__global__ void k_detect(const unsigned int* __restrict__ emb_raw, int* __restrict__ flag){
  if(threadIdx.x==0){
    unsigned v=0;
    for(int i=16;i<32;i++) v |= emb_raw[i];
    flag[0] = v ? 1 : 0;   // 1 = bf16 inputs, 0 = f32 inputs
  }
}

// -------- weight prep: (bf16|f32) -> fp32 ------------------------------------------
struct PrepArgs { const void* s[22]; int off[22]; int sz[22]; int trR[22]; int soff[22]; int pk[22]; };

__global__ void k_prep(PrepArgs a, float* __restrict__ W, const int* __restrict__ flag){
  int bf = flag[0];
  int seg = blockIdx.y;
  int i = blockIdx.x*256 + threadIdx.x;
  if(i >= a.sz[seg]) return;
  int R = a.trR[seg];
  int P = a.pk[seg];
  int sidx;
  if(P){
    int c = i/(4*P); int rem = i%(4*P); int col = rem>>2; int s = rem&3;
    sidx = col*DD + 4*c + s;
  } else if(R){ int C = a.sz[seg]/R; sidx = (i%R)*C + (i/R); } else sidx = i;
  sidx += a.soff[seg];
  float v = bf ? bf2f(((const unsigned short*)a.s[seg])[sidx])
               : ((const float*)a.s[seg])[sidx];
  W[a.off[seg]+i] = v;
}

// ---- pack GRU gate weights into fp16 MFMA B-fragments (16x16x16f16 layout) ----
__global__ void k_prep16(const float* __restrict__ Wall, __half* __restrict__ F){
  int id = blockIdx.x*256 + threadIdx.x;
  if(id >= 6144) return;
  int e  = id & 3;
  int l  = (id >> 2) & 63;
  int kh = (id >> 8) & 1;
  int tmp = id >> 9;
  int jt  = tmp % 6;
  int reg = tmp / 6;
  int j = 16*jt + (l & 15);
  int k = 16*kh + 4*(l >> 4) + e;
  int srcoff = (reg==0 ? OFF_WIHGT : OFF_WHHGT) + j*DD + k;
  F[id] = __float2half(Wall[srcoff]);
}

// ---------------- lin0: h0[n] = fp16(relu(W0 @ emb[node_type[n]] + b0)) -----------
__global__ void k_lin0(const int* __restrict__ nt, const float* __restrict__ Wall,
                       __half* __restrict__ hmir){
  int n = blockIdx.x*blockDim.x + threadIdx.x;
  if(n >= N_) return;
  const float* er  = Wall + OFF_EMB + nt[n]*DD;
  const float* W0T = Wall + OFF_W0T;
  const float* b0  = Wall + OFF_B0;
  float m[DD];
  #pragma unroll
  for(int j=0;j<DD;j++) m[j]=b0[j];
  #pragma unroll 4
  for(int k=0;k<DD;k++){
    float xk = er[k];
    #pragma unroll
    for(int j=0;j<DD;j++) m[j] = __fmaf_rn(W0T[k*DD+j], xk, m[j]);
  }
  __half* hrow = hmir + (size_t)n*DD;
  #pragma unroll
  for(int j=0;j<DD;j++) hrow[j]=__float2half(fmaxf(m[j],0.f));
}

// ---------------- CSR build (r10 proven: rank-from-atomic, atomic-free scatter) ----
__global__ void k_deg(const int* __restrict__ dst, int* __restrict__ deg,
                      int* __restrict__ key){
  int e = blockIdx.x*blockDim.x + threadIdx.x;
  if(e < E_){
    int d = dst[e];
    int old = atomicAdd(&deg[d], 1);
    key[e] = d | (old << 18);     // d < 2^18, rank < 2^14
  }
}
__global__ void __launch_bounds__(1024) k_scanA(const int* __restrict__ deg,
                       int* __restrict__ incl, int* __restrict__ bsum){
  __shared__ int sh[1024];
  int g = blockIdx.x*1024 + threadIdx.x;
  int v = (g < N_) ? deg[g] : 0;
  sh[threadIdx.x]=v; __syncthreads();
  for(int o=1;o<1024;o<<=1){
    int a = (threadIdx.x>=o) ? sh[threadIdx.x-o] : 0;
    __syncthreads();
    sh[threadIdx.x]+=a;
    __syncthreads();
  }
  if(g < N_) incl[g]=sh[threadIdx.x];
  if(threadIdx.x==1023) bsum[blockIdx.x]=sh[1023];
}
__global__ void k_scanB(const int* __restrict__ bsum, int* __restrict__ boff){
  __shared__ int sh[256];
  int t=threadIdx.x;
  int v=(t<196)?bsum[t]:0;
  sh[t]=v; __syncthreads();
  for(int o=1;o<256;o<<=1){
    int a=(t>=o)?sh[t-o]:0; __syncthreads(); sh[t]+=a; __syncthreads();
  }
  if(t<196) boff[t]=sh[t]-v;   // exclusive
}
__global__ void __launch_bounds__(1024) k_scanC(const int* __restrict__ deg,
                       const int* __restrict__ boff, int* __restrict__ noff,
                       int* __restrict__ incl_cursor){
  int g = blockIdx.x*1024 + threadIdx.x;
  if(g >= N_) return;
  int ex = incl_cursor[g] - deg[g] + boff[g>>10];
  noff[g]=ex; incl_cursor[g]=ex;   // cursor = exclusive offset
}
// goff[g] = lower_bound(gid, g)  (gid sorted)
__global__ void k_goff(const int* __restrict__ gid, int* __restrict__ goff){
  int g = blockIdx.x*256 + threadIdx.x;
  if(g > B_) return;
  int lo=0, hi=N_;
  while(lo<hi){ int mid=(lo+hi)>>1; if(gid[mid]<g) lo=mid+1; else hi=mid; }
  goff[g]=lo;
}
// atomic-free scatter: position = noff[d] + precomputed rank
__global__ void k_scatter(const int* __restrict__ src, const int* __restrict__ key,
                          const int* __restrict__ noff, int* __restrict__ csr){
  int e = blockIdx.x*256 + threadIdx.x;
  int k = key[e];
  int d = k & 0x3FFFF;
  int p = noff[d] + (k >> 18);
  csr[p] = src[e];
}

// ---- fused step, MFMA edition --------------------------------------------------
// gather v5 = r13 LDS index staging + PAIRED phases: each thread gathers TWO nodes'
// batches concurrently (16 in-flight row fetches/lane vs 8) before reducing either
// -> 2x per-wave MLP at ~same segments/instr (the r12 regression's cause, avoided).
__global__ void __launch_bounds__(256) k_step(const float* __restrict__ Wall,
                       const __half* __restrict__ F16, const int* __restrict__ noff,
                       const int* __restrict__ deg, const int* __restrict__ csr,
                       const __half* __restrict__ curh, __half* __restrict__ nxth){
  __shared__ __align__(16) float  lds_acc[4][4][DD];
  __shared__ __align__(16) __half lds_m[4][16][40];
  __shared__ int lds_idx[4][IDXCAP];
  __shared__ int lds_nd[4][32];          // [0..15]=noff, [16..31]=deg
  const int t = threadIdx.x;
  const int w = t >> 6, l = t & 63;
  const int d = l & 31, half = l >> 5;
  const int q  = d >> 3;        // edge subgroup 0..3
  const int r8 = d & 7;         // dim-quad index: dims 4*r8 .. 4*r8+3
  const int n0 = blockIdx.x*64 + w*16;
  const float4* WmP = (const float4*)(Wall + OFF_WMT);
  const __half* rowbase = curh + 4*r8;   // per-lane fixed dim offset
  // ---- stage node meta + edge indices (wave-private; in-order DS pipe) ----
  if(l < 16){
    lds_nd[w][l]    = noff[n0+l];
    lds_nd[w][16+l] = deg[n0+l];
  }
  int s_begin = lds_nd[w][0];
  int total   = lds_nd[w][15] + lds_nd[w][31] - s_begin;
  int tc = total < IDXCAP ? total : IDXCAP;
  for(int i=l; i<tc; i+=64) lds_idx[w][i] = csr[s_begin+i];
  // ---- phase 1 ----
  if(total <= IDXCAP){
    // paired phases: nodes iA=4pp+half and iB=4pp+2+half gathered concurrently
    for(int pp=0;pp<4;pp++){
      int iA = 4*pp + half, iB = iA + 2;
      int sA = lds_nd[w][iA] - s_begin, lA = lds_nd[w][16+iA];
      int sB = lds_nd[w][iB] - s_begin, lB = lds_nd[w][16+iB];
      const int* ipA = &lds_idx[w][sA];
      const int* ipB = &lds_idx[w][sB];
      float aA0=0.f,aA1=0.f,aA2=0.f,aA3=0.f;
      float aB0=0.f,aB1=0.f,aB2=0.f,aB3=0.f;
      int ml = lA > lB ? lA : lB;
      for(int i=0; i<ml; i+=32){
        int rA = lA - i, rB = lB - i;
        if(rA > 0) gbatch(ipA, i, rA, rowbase, q, aA0,aA1,aA2,aA3);
        if(rB > 0) gbatch(ipB, i, rB, rowbase, q, aB0,aB1,aB2,aB3);
      }
      #pragma unroll
      for(int off=8; off<=16; off<<=1){
        aA0 += __shfl_xor(aA0, off, 32); aA1 += __shfl_xor(aA1, off, 32);
        aA2 += __shfl_xor(aA2, off, 32); aA3 += __shfl_xor(aA3, off, 32);
        aB0 += __shfl_xor(aB0, off, 32); aB1 += __shfl_xor(aB1, off, 32);
        aB2 += __shfl_xor(aB2, off, 32); aB3 += __shfl_xor(aB3, off, 32);
      }
      int lsrc = d >> 2;
      float vA0=__shfl(aA0,lsrc,32), vA1=__shfl(aA1,lsrc,32);
      float vA2=__shfl(aA2,lsrc,32), vA3=__shfl(aA3,lsrc,32);
      float vB0=__shfl(aB0,lsrc,32), vB1=__shfl(aB1,lsrc,32);
      float vB2=__shfl(aB2,lsrc,32), vB3=__shfl(aB3,lsrc,32);
      float accA = (d&1) ? ((d&2)? vA3 : vA1) : ((d&2)? vA2 : vA0);
      float accB = (d&1) ? ((d&2)? vB3 : vB1) : ((d&2)? vB2 : vB0);
      lds_acc[w][half][d]   = accA;
      lds_acc[w][2+half][d] = accB;
      const float4* acA = (const float4*)(&lds_acc[w][half][0]);
      const float4* acB = (const float4*)(&lds_acc[w][2+half][0]);
      float mA = 0.f, mB = 0.f;
      #pragma unroll
      for(int c=0;c<8;c++){
        float4 wv = WmP[c*32 + d];
        float4 avA = acA[c];
        float4 avB = acB[c];
        mA = __fmaf_rn(wv.x, avA.x, mA); mB = __fmaf_rn(wv.x, avB.x, mB);
        mA = __fmaf_rn(wv.y, avA.y, mA); mB = __fmaf_rn(wv.y, avB.y, mB);
        mA = __fmaf_rn(wv.z, avA.z, mA); mB = __fmaf_rn(wv.z, avB.z, mB);
        mA = __fmaf_rn(wv.w, avA.w, mA); mB = __fmaf_rn(wv.w, avB.w, mB);
      }
      lds_m[w][iA][d] = __float2half(fmaxf(mA, 0.f));
      lds_m[w][iB][d] = __float2half(fmaxf(mB, 0.f));
    }
  } else {
    // cold fallback (range > IDXCAP): r13 sequential direct-csr path
    for(int p=0;p<8;p++){
      int ni = 2*p + half;
      int s0 = lds_nd[w][ni];
      int len = lds_nd[w][16+ni];
      float a0=0.f, a1=0.f, a2=0.f, a3=0.f;
      for(int i=0; i<len; i+=32){
        int rem = len - i;
        gbatch(csr + s0, i, rem, rowbase, q, a0,a1,a2,a3);
      }
      #pragma unroll
      for(int off=8; off<=16; off<<=1){
        a0 += __shfl_xor(a0, off, 32);
        a1 += __shfl_xor(a1, off, 32);
        a2 += __shfl_xor(a2, off, 32);
        a3 += __shfl_xor(a3, off, 32);
      }
      float v0 = __shfl(a0, d>>2, 32);
      float v1 = __shfl(a1, d>>2, 32);
      float v2 = __shfl(a2, d>>2, 32);
      float v3 = __shfl(a3, d>>2, 32);
      float accd = (d&1) ? ((d&2)? v3 : v1) : ((d&2)? v2 : v0);
      lds_acc[w][half][d] = accd;
      const float4* ac = (const float4*)(&lds_acc[w][half][0]);
      float m = 0.f;
      #pragma unroll
      for(int c=0;c<8;c++){
        float4 wv = WmP[c*32 + d];
        float4 av = ac[c];
        m = __fmaf_rn(wv.x, av.x, m);
        m = __fmaf_rn(wv.y, av.y, m);
        m = __fmaf_rn(wv.z, av.z, m);
        m = __fmaf_rn(wv.w, av.w, m);
      }
      lds_m[w][2*p+half][d] = __float2half(fmaxf(m, 0.f));
    }
  }
  // ---- phase 2 ----
  const int rowa = l & 15, grp = l >> 4;
  f16x4 Am0 = *(const f16x4*)((const void*)&lds_m[w][rowa][4*grp]);
  f16x4 Am1 = *(const f16x4*)((const void*)&lds_m[w][rowa][16 + 4*grp]);
  const __half* hrow = curh + (size_t)(n0 + rowa)*DD;
  f16x4 Ah0 = *(const f16x4*)((const void*)(hrow + 4*grp));
  f16x4 Ah1 = *(const f16x4*)((const void*)(hrow + 16 + 4*grp));
  const f16x4* Bf = (const f16x4*)F16;
  f32x4 Drz[4], Din[2], Dhn[2];
  #pragma unroll
  for(int jt=0;jt<4;jt++){
    f32x4 a = {0.f,0.f,0.f,0.f};
    a = __builtin_amdgcn_mfma_f32_16x16x16f16(Ah0, Bf[(12 + jt*2    )*64 + l], a, 0,0,0);
    a = __builtin_amdgcn_mfma_f32_16x16x16f16(Ah1, Bf[(12 + jt*2 + 1)*64 + l], a, 0,0,0);
    a = __builtin_amdgcn_mfma_f32_16x16x16f16(Am0, Bf[(     jt*2    )*64 + l], a, 0,0,0);
    a = __builtin_amdgcn_mfma_f32_16x16x16f16(Am1, Bf[(     jt*2 + 1)*64 + l], a, 0,0,0);
    Drz[jt] = a;
  }
  #pragma unroll
  for(int s=0;s<2;s++){
    int jt = 4 + s;
    f32x4 a = {0.f,0.f,0.f,0.f};
    f32x4 b = {0.f,0.f,0.f,0.f};
    a = __builtin_amdgcn_mfma_f32_16x16x16f16(Am0, Bf[(     jt*2    )*64 + l], a, 0,0,0);
    a = __builtin_amdgcn_mfma_f32_16x16x16f16(Am1, Bf[(     jt*2 + 1)*64 + l], a, 0,0,0);
    b = __builtin_amdgcn_mfma_f32_16x16x16f16(Ah0, Bf[(12 + jt*2    )*64 + l], b, 0,0,0);
    b = __builtin_amdgcn_mfma_f32_16x16x16f16(Ah1, Bf[(12 + jt*2 + 1)*64 + l], b, 0,0,0);
    Din[s] = a; Dhn[s] = b;
  }
  #pragma unroll
  for(int s=0;s<2;s++){
    int dd = 16*s + rowa;
    float br = Wall[OFF_BIHG+dd]      + Wall[OFF_BHHG+dd];
    float bz = Wall[OFF_BIHG+DD+dd]   + Wall[OFF_BHHG+DD+dd];
    float bi = Wall[OFF_BIHG+2*DD+dd];
    float bh = Wall[OFF_BHHG+2*DD+dd];
    #pragma unroll
    for(int r=0;r<4;r++){
      int node = n0 + grp*4 + r;
      float hv = __half2float(curh[(size_t)node*DD + dd]);
      float rr = sigm(Drz[s][r]   + br);
      float zz = sigm(Drz[2+s][r] + bz);
      float nn = tanhfast((Din[s][r] + bi) + rr*(Dhn[s][r] + bh));
      nxth[(size_t)node*DD + dd] = __float2half((1.f - zz)*nn + zz*hv);
    }
  }
}

// ---- Set2Set + readout: block g owns graph g; 1024 thr = 16 waves (r7 win) -------
#define MAXEV 1024
__global__ void __launch_bounds__(1024, 8) k_s2s(const float* __restrict__ Wall,
                       const __half* __restrict__ hstate, const int* __restrict__ goff,
                       void* __restrict__ op, const int* __restrict__ flag){
  int g = blockIdx.x, t = threadIdx.x;
  int l32 = t & 31, g32 = t >> 5;        // 32 row-groups of 32 lanes
  __shared__ float evb[MAXEV];
  __shared__ float red[32*33];           // pass3 transpose-reduce, padded
  __shared__ float wred[16];
  __shared__ float qs[64];
  __shared__ float xb[64];
  __shared__ float hb[3][32];
  __shared__ float gbuf[128];
  __shared__ float yb[32];
  __shared__ float bc_mx, bc_inv;
  int s0 = goff[g], s1 = goff[g+1];
  int len = s1 - s0;
  int lc = len < MAXEV ? len : MAXEV;
  if(t < 64) qs[t] = 0.f;
  if(t < 96) hb[t>>5][t&31] = 0.f;
  float c0=0.f, c1=0.f, c2v=0.f;           // cell states on threads 0..31
  __syncthreads();
  for(int it=0; it<6; it++){
    if(t<64) xb[t]=qs[t];
    __syncthreads();
    // ---- LSTM layer 0 (xdim 64) ----
    if(t<128){
      const float* WT = Wall + OFF_WIH0T; const float* UT = Wall + OFF_WHH0T;
      float gv = Wall[OFF_BIH0+t] + Wall[OFF_BHH0+t];
      #pragma unroll 8
      for(int k=0;k<64;k++) gv = __fmaf_rn(WT[k*128+t], xb[k], gv);
      #pragma unroll 8
      for(int k=0;k<32;k++) gv = __fmaf_rn(UT[k*128+t], hb[0][k], gv);
      gbuf[t]=gv;
    }
    __syncthreads();
    if(t<32){
      float iv=sigm(gbuf[t]), fv=sigm(gbuf[32+t]), gg=tanhfast(gbuf[64+t]), ov=sigm(gbuf[96+t]);
      float c = fv*c0 + iv*gg; c0=c;
      float h2 = ov*tanhfast(c);
      hb[0][t]=h2; xb[t]=h2;
    }
    __syncthreads();
    // ---- LSTM layers 1,2 (xdim 32) ----
    for(int l=1;l<3;l++){
      if(t<128){
        const float* WT = Wall + (l==1?OFF_WIH1T:OFF_WIH2T);
        const float* UT = Wall + (l==1?OFF_WHH1T:OFF_WHH2T);
        int bo=(l-1)*128;
        float gv = Wall[OFF_BIH12+bo+t] + Wall[OFF_BHH12+bo+t];
        #pragma unroll 8
        for(int k=0;k<32;k++) gv = __fmaf_rn(WT[k*128+t], xb[k], gv);
        #pragma unroll 8
        for(int k=0;k<32;k++) gv = __fmaf_rn(UT[k*128+t], hb[l][k], gv);
        gbuf[t]=gv;
      }
      __syncthreads();
      if(t<32){
        float cp = (l==1)?c1:c2v;
        float iv=sigm(gbuf[t]), fv=sigm(gbuf[32+t]), gg=tanhfast(gbuf[64+t]), ov=sigm(gbuf[96+t]);
        float c = fv*cp + iv*gg;
        if(l==1) c1=c; else c2v=c;
        float h2 = ov*tanhfast(c);
        hb[l][t]=h2; xb[t]=h2;
      }
      __syncthreads();
    }
    float q = xb[l32];                     // layer-2 h, per-lane
    // ---- pass 1: logits + max ----
    float lmax = -INFINITY;
    for(int i=g32; i<len; i+=32){
      float v = __half2float(hstate[(size_t)(s0+i)*DD+l32])*q;
      #pragma unroll
      for(int o=16;o>0;o>>=1) v += __shfl_xor(v,o,32);
      if(i<lc && l32==0) evb[i]=v;
      lmax = fmaxf(lmax, v);
    }
    lmax = fmaxf(lmax, __shfl_xor(lmax, 32, 64));
    if((t&63)==0) wred[t>>6]=lmax;
    __syncthreads();
    if(t==0){ float m=wred[0];
      #pragma unroll
      for(int k=1;k<16;k++) m=fmaxf(m,wred[k]);
      bc_mx=m; }
    __syncthreads();
    float mx = bc_mx;
    // ---- pass 2: exp + sum; cache exp into evb ----
    float sm=0.f;
    for(int i=t;i<len;i+=1024){
      float v;
      if(i<lc) v=evb[i];
      else { v=0.f; for(int k=0;k<DD;k++) v += __half2float(hstate[(size_t)(s0+i)*DD+k])*xb[k]; }
      float e = __expf(v-mx);
      if(i<lc) evb[i]=e;
      sm += e;
    }
    #pragma unroll
    for(int o=32;o>0;o>>=1) sm += __shfl_xor(sm,o,64);
    if((t&63)==0) wred[t>>6]=sm;
    __syncthreads();
    if(t==0){ float s=0.f;
      #pragma unroll
      for(int k=0;k<16;k++) s+=wred[k];
      bc_inv = (s>0.f) ? 1.f/s : 0.f; }
    __syncthreads();
    float inv = bc_inv;
    // ---- pass 3: weighted sum ----
    float acc=0.f;
    for(int i=g32;i<len;i+=32){
      float fv = __half2float(hstate[(size_t)(s0+i)*DD+l32]);
      float wgt;
      if(i<lc) wgt=evb[i];
      else { float vv=fv*q;
             #pragma unroll
             for(int o=16;o>0;o>>=1) vv += __shfl_xor(vv,o,32);
             wgt=__expf(vv-mx); }
      acc = __fmaf_rn(wgt, fv, acc);
    }
    red[g32*33+l32]=acc; __syncthreads();
    if(t<32){
      float s=0.f;
      #pragma unroll
      for(int k=0;k<32;k++) s+=red[k*33+t];
      qs[32+t]=s*inv; qs[t]=xb[t];
    }
    __syncthreads();
  }
  // ---- readout MLP ----
  if(t<32){
    const float* W1 = Wall+OFF_WR1T;
    float s = Wall[OFF_BR1+t];
    #pragma unroll 8
    for(int k=0;k<64;k++) s = __fmaf_rn(W1[k*32+t], qs[k], s);
    yb[t]=fmaxf(s,0.f);
  }
  __syncthreads();
  if(t<32){
    const float* W2 = Wall+OFF_WR2T;
    float o = Wall[OFF_BR2+t];
    #pragma unroll 8
    for(int k=0;k<32;k++) o = __fmaf_rn(W2[k*32+t], yb[k], o);
    if(flag[0]) ((__hip_bfloat16*)op)[g*32+t]=__float2bfloat16(o);
    else        ((float*)op)[g*32+t]=o;
  }
}

extern "C" void kernel_launch(void* const* d_in, const int* in_sizes, int n_in,
                              void* d_out, int out_size, void* d_ws, size_t ws_size,
                              hipStream_t stream) {
  const int* nt  = (const int*)d_in[0];
  const int* src = (const int*)d_in[1];
  const int* dst = (const int*)d_in[2];
  const int* gid = (const int*)d_in[3];
  float* W = (float*)d_ws;
  char* base = (char*)d_ws;
  __half* F16 = (__half*)(base + F16_BYTE);
  __half* h0 = (__half*)(base + H0_BYTE);
  __half* h1 = (__half*)(base + H1_BYTE);
  int* I = (int*)(base + INT_BASE);
  int* deg=I+I_DEG; int* noff=I+I_NOFF; int* cursor=I+I_CURSOR;
  int* goff=I+I_GOFF; int* bsum=I+I_BSUM; int* boff=I+I_BOFF; int* csr=I+I_CSR;
  int* flag=I+I_FLAG;
  // edge-rank key temp reuses h1 (E ints = 12.8 MB); h1 is first written by
  // k_step step 0, strictly after scatter completes. k_deg rewrites every launch.
  int* key = (int*)h1;

  hipMemsetAsync(deg, 0, (size_t)N_*4, stream);

  k_detect<<<1,64,0,stream>>>((const unsigned int*)d_in[4], flag);

  PrepArgs pa;
  const int sidx[22]={4,6,10,11,14,15,18,19,21,23, 5,7,8,9,12,13,16,16,17,17,20,22};
  const int offs[22]={OFF_EMB,OFF_B0,OFF_BIHG,OFF_BHHG,OFF_BIH0,OFF_BHH0,OFF_BIH12,
                      OFF_BHH12,OFF_BR1,OFF_BR2, OFF_W0T,OFF_WMT,OFF_WIHGT,OFF_WHHGT,
                      OFF_WIH0T,OFF_WHH0T,OFF_WIH1T,OFF_WIH2T,OFF_WHH1T,OFF_WHH2T,
                      OFF_WR1T,OFF_WR2T};
  const int szs[22]={3232,32,96,96,128,128,256,256,32,32, 1024,1024,3072,3072,
                     8192,4096,4096,4096,4096,4096,2048,1024};
  // Wm chunk-packed fp32 (float4 matvec); Wih_g/Whh_g plain [96][32] (k_prep16 source)
  const int trR[22]={0,0,0,0,0,0,0,0,0,0, 32,0,0,0,128,128,128,128,128,128,32,32};
  const int pkv[22]={0,0,0,0,0,0,0,0,0,0, 0,32,0,0,0,0,0,0,0,0,0,0};
  const int sof[22]={0,0,0,0,0,0,0,0,0,0, 0,0,0,0,0,0,0,4096,0,4096,0,0};
  for(int i=0;i<22;i++){ pa.s[i]=d_in[sidx[i]]; pa.off[i]=offs[i]; pa.sz[i]=szs[i];
                         pa.trR[i]=trR[i]; pa.soff[i]=sof[i]; pa.pk[i]=pkv[i]; }
  hipLaunchKernelGGL(k_prep, dim3(32,22), dim3(256), 0, stream, pa, W, flag);
  k_prep16<<<24,256,0,stream>>>(W, F16);

  k_lin0<<<782,256,0,stream>>>(nt, W, h0);
  k_deg<<<12500,256,0,stream>>>(dst, deg, key);
  k_scanA<<<196,1024,0,stream>>>(deg, cursor, bsum);
  k_scanB<<<1,256,0,stream>>>(bsum, boff);
  k_scanC<<<196,1024,0,stream>>>(deg, boff, noff, cursor);
  k_goff<<<3,256,0,stream>>>(gid, goff);
  k_scatter<<<12500,256,0,stream>>>(src, key, noff, csr);

  // 6 MP steps on fp16 double-buffered state (even count -> final state in h0)
  __half* curh = h0; __half* nxth = h1;
  for(int s=0;s<6;s++){
    k_step<<<3125,256,0,stream>>>(W, F16, noff, deg, csr, curh, nxth);
    __half* tmp = curh; curh = nxth; nxth = tmp;
  }
  // whole Set2Set + readout in one launch (block g == graph g, fully independent)
  k_s2s<<<B_,1024,0,stream>>>(W, curh, goff, d_out, flag);
}

// Round 16
// 690.045 us; speedup vs baseline: 1.5452x; 1.1598x over previous
//
#include <hip/hip_runtime.h>
#include <hip/hip_bf16.h>
#include <hip/hip_fp16.h>

#define DD 32
constexpr int N_ = 200000;
constexpr int E_ = 3200000;
constexpr int B_ = 512;
constexpr int IDXCAP = 768;      // per-wave staged edge-index capacity
constexpr int NBUCK = 782;       // coarse buckets of 256 nodes (bucket = dst>>8)
constexpr int NBLKA = 256;       // blocks in count/scatter passes
constexpr int EPB   = E_/NBLKA;  // 12500 edges per block (exact)

typedef _Float16 f16x4 __attribute__((ext_vector_type(4)));
typedef float f32x4 __attribute__((ext_vector_type(4)));

// ---------------- workspace layout ----------------
constexpr int OFF_EMB=0, OFF_B0=3232, OFF_BIHG=3264, OFF_BHHG=3360, OFF_BIH0=3456,
  OFF_BHH0=3584, OFF_BIH12=3712, OFF_BHH12=3968, OFF_BR1=4224, OFF_BR2=4256,
  OFF_W0T=4288, OFF_WMT=5312, OFF_WIHGT=6336, OFF_WHHGT=9408,
  OFF_WIH0T=12480, OFF_WHH0T=20672, OFF_WIH1T=24768, OFF_WHH1T=28864,
  OFF_WIH2T=32960, OFF_WHH2T=37056, OFF_WR1T=41152, OFF_WR2T=43200;
constexpr long FLOAT_END=44288L;
// fp16 MFMA weight-fragment region (6144 halfs = 12288 B), then fp16 states
constexpr size_t F16_BYTE = (size_t)FLOAT_END*4;           // 177152
constexpr size_t H0_BYTE  = F16_BYTE + 12288;              // 189440
constexpr size_t H1_BYTE  = H0_BYTE + (size_t)N_*DD*2;     // fp16 state B
constexpr size_t INT_BASE = H1_BYTE + (size_t)N_*DD*2;     // 25789440, 256B aligned
// int offsets (in ints, from INT_BASE)
constexpr int I_DEG=0, I_NOFF=200512, I_CNT=400512, I_GOFF=600512,
  I_CSR=601600;                          // csr: E ints
constexpr int I_FLAG=3801600;
constexpr int I_TOT=3801664, I_BBASE=3802496;   // 782 + 783 ints

__device__ __forceinline__ float bf2f(unsigned short u){ return __uint_as_float(((unsigned)u)<<16); }
__device__ __forceinline__ float sigm(float x){ return 1.0f/(1.0f+__expf(-x)); }
__device__ __forceinline__ float tanhfast(float x){ return 1.0f - 2.0f/(__expf(2.0f*x)+1.0f); }

// one 8-slot predicated gather batch (32 edges across 4 lane-subgroups)
__device__ __forceinline__ void gbatch(const int* __restrict__ ip, int i, int rem,
                                       const __half* __restrict__ rowbase, int q,
                                       float& a0, float& a1, float& a2, float& a3){
  #pragma unroll
  for(int s=0;s<8;s++){
    int e  = 4*s + q;
    int ec = e < rem ? e : rem-1;
    int idx = ip[i + ec];
    uint2 v = *(const uint2*)(rowbase + (size_t)idx*DD);
    if(e >= rem){ v.x = 0u; v.y = 0u; }
    float2 f0 = __half22float2(*(__half2*)&v.x);
    float2 f1 = __half22float2(*(__half2*)&v.y);
    a0 += f0.x; a1 += f0.y; a2 += f1.x; a3 += f1.y;
  }
}

// ---------------- input-dtype detection ----------------
__global__ void k_detect(const unsigned int* __restrict__ emb_raw, int* __restrict__ flag){
  if(threadIdx.x==0){
    unsigned v=0;
    for(int i=16;i<32;i++) v |= emb_raw[i];
    flag[0] = v ? 1 : 0;   // 1 = bf16 inputs, 0 = f32 inputs
  }
}

// -------- weight prep: (bf16|f32) -> fp32 ------------------------------------------
struct PrepArgs { const void* s[22]; int off[22]; int sz[22]; int trR[22]; int soff[22]; int pk[22]; };

__global__ void k_prep(PrepArgs a, float* __restrict__ W, const int* __restrict__ flag){
  int bf = flag[0];
  int seg = blockIdx.y;
  int i = blockIdx.x*256 + threadIdx.x;
  if(i >= a.sz[seg]) return;
  int R = a.trR[seg];
  int P = a.pk[seg];
  int sidx;
  if(P){
    int c = i/(4*P); int rem = i%(4*P); int col = rem>>2; int s = rem&3;
    sidx = col*DD + 4*c + s;
  } else if(R){ int C = a.sz[seg]/R; sidx = (i%R)*C + (i/R); } else sidx = i;
  sidx += a.soff[seg];
  float v = bf ? bf2f(((const unsigned short*)a.s[seg])[sidx])
               : ((const float*)a.s[seg])[sidx];
  W[a.off[seg]+i] = v;
}

// ---- pack GRU gate weights into fp16 MFMA B-fragments (16x16x16f16 layout) ----
__global__ void k_prep16(const float* __restrict__ Wall, __half* __restrict__ F){
  int id = blockIdx.x*256 + threadIdx.x;
  if(id >= 6144) return;
  int e  = id & 3;
  int l  = (id >> 2) & 63;
  int kh = (id >> 8) & 1;
  int tmp = id >> 9;
  int jt  = tmp % 6;
  int reg = tmp / 6;
  int j = 16*jt + (l & 15);
  int k = 16*kh + 4*(l >> 4) + e;
  int srcoff = (reg==0 ? OFF_WIHGT : OFF_WHHGT) + j*DD + k;
  F[id] = __float2half(Wall[srcoff]);
}

// ---------------- lin0: h0[n] = fp16(relu(W0 @ emb[node_type[n]] + b0)) -----------
__global__ void k_lin0(const int* __restrict__ nt, const float* __restrict__ Wall,
                       __half* __restrict__ hmir){
  int n = blockIdx.x*blockDim.x + threadIdx.x;
  if(n >= N_) return;
  const float* er  = Wall + OFF_EMB + nt[n]*DD;
  const float* W0T = Wall + OFF_W0T;
  const float* b0  = Wall + OFF_B0;
  float m[DD];
  #pragma unroll
  for(int j=0;j<DD;j++) m[j]=b0[j];
  #pragma unroll 4
  for(int k=0;k<DD;k++){
    float xk = er[k];
    #pragma unroll
    for(int j=0;j<DD;j++) m[j] = __fmaf_rn(W0T[k*DD+j], xk, m[j]);
  }
  __half* hrow = hmir + (size_t)n*DD;
  #pragma unroll
  for(int j=0;j<DD;j++) hrow[j]=__float2half(fmaxf(m[j],0.f));
}

// ---------------- CSR build v2: bucket sort, ZERO global atomics ----------------
// r11 proved k_deg's 3.2M device-scope atomics are op-rate-bound (~145us floor,
// replication changed nothing). Replace the whole build with LDS-atomic bucket sort.
// pass 1: per-block LDS histogram over 782 coarse buckets -> count columns
__global__ void __launch_bounds__(256) k_bcnt(const int* __restrict__ dst,
                                              int* __restrict__ cnt){
  __shared__ int h[NBUCK];
  int blk = blockIdx.x, t = threadIdx.x;
  for(int i=t;i<NBUCK;i+=256) h[i]=0;
  __syncthreads();
  int e0 = blk*EPB;
  for(int i=t;i<EPB;i+=256) atomicAdd(&h[dst[e0+i]>>8], 1);
  __syncthreads();
  for(int i=t;i<NBUCK;i+=256) cnt[blk*NBUCK+i]=h[i];
}
// pass 2a: column-exclusive scan over the 256 blocks, per bucket
__global__ void __launch_bounds__(256) k_bscan1(int* __restrict__ cnt,
                                                int* __restrict__ total){
  __shared__ int sh[256];
  int b = blockIdx.x, t = threadIdx.x;
  int v = cnt[t*NBUCK + b];
  sh[t]=v; __syncthreads();
  for(int o=1;o<256;o<<=1){ int a=(t>=o)?sh[t-o]:0; __syncthreads(); sh[t]+=a; __syncthreads(); }
  cnt[t*NBUCK+b] = sh[t]-v;   // exclusive within column
  if(t==255) total[b]=sh[255];
}
// pass 2b: exclusive scan of bucket totals -> bucket bases (bbase[NBUCK] = E)
__global__ void __launch_bounds__(1024) k_bscan2(const int* __restrict__ total,
                                                 int* __restrict__ bbase){
  __shared__ int sh[1024];
  int t=threadIdx.x;
  int v = (t<NBUCK)? total[t] : 0;
  sh[t]=v; __syncthreads();
  for(int o=1;o<1024;o<<=1){ int a=(t>=o)?sh[t-o]:0; __syncthreads(); sh[t]+=a; __syncthreads(); }
  if(t<NBUCK) bbase[t]=sh[t]-v;
  if(t==NBUCK-1) bbase[NBUCK]=sh[t];
}
// pass 3: scatter edges into bucket order, packed (src | localnode<<18). LDS cursors.
__global__ void __launch_bounds__(256) k_bscat(const int* __restrict__ src,
                        const int* __restrict__ dst, const int* __restrict__ cnt,
                        const int* __restrict__ bbase, int* __restrict__ bucketed){
  __shared__ int loff[NBUCK];
  int blk = blockIdx.x, t = threadIdx.x;
  for(int i=t;i<NBUCK;i+=256) loff[i] = bbase[i] + cnt[blk*NBUCK+i];
  __syncthreads();
  int e0 = blk*EPB;
  for(int i=t;i<EPB;i+=256){
    int e = e0+i;
    int d = dst[e];
    int p = atomicAdd(&loff[d>>8], 1);
    bucketed[p] = src[e] | ((d & 255) << 18);
  }
}
// pass 4: per-bucket fine CSR: deg + noff (replaces the global scans) + csr.
// csr writes land in a ~16KB bucket region -> no scatter write amplification.
__global__ void __launch_bounds__(256) k_bfine(const int* __restrict__ bucketed,
                        const int* __restrict__ bbase, int* __restrict__ deg,
                        int* __restrict__ noff, int* __restrict__ csr){
  __shared__ int cnt[256];
  __shared__ int sc[256];
  int b = blockIdx.x, t = threadIdx.x;
  int base = bbase[b], end = bbase[b+1];
  cnt[t]=0;
  __syncthreads();
  for(int i=base+t; i<end; i+=256) atomicAdd(&cnt[(bucketed[i]>>18)&255], 1);
  __syncthreads();
  int v = cnt[t];
  sc[t]=v; __syncthreads();
  for(int o=1;o<256;o<<=1){ int a=(t>=o)?sc[t-o]:0; __syncthreads(); sc[t]+=a; __syncthreads(); }
  int excl = sc[t]-v;
  int n = b*256+t;
  if(n < N_){ deg[n]=v; noff[n]=base+excl; }
  __syncthreads();
  sc[t]=excl; cnt[t]=0;
  __syncthreads();
  for(int i=base+t; i<end; i+=256){
    int pv = bucketed[i];
    int loc = (pv>>18)&255;
    int r = atomicAdd(&cnt[loc], 1);
    csr[base + sc[loc] + r] = pv & 0x3FFFF;
  }
}
// goff[g] = lower_bound(gid, g)  (gid sorted)
__global__ void k_goff(const int* __restrict__ gid, int* __restrict__ goff){
  int g = blockIdx.x*256 + threadIdx.x;
  if(g > B_) return;
  int lo=0, hi=N_;
  while(lo<hi){ int mid=(lo+hi)>>1; if(gid[mid]<g) lo=mid+1; else hi=mid; }
  goff[g]=lo;
}

// ---- fused step, MFMA edition (r15 winner: LDS idx staging + paired phases) ------
__global__ void __launch_bounds__(256) k_step(const float* __restrict__ Wall,
                       const __half* __restrict__ F16, const int* __restrict__ noff,
                       const int* __restrict__ deg, const int* __restrict__ csr,
                       const __half* __restrict__ curh, __half* __restrict__ nxth){
  __shared__ __align__(16) float  lds_acc[4][4][DD];
  __shared__ __align__(16) __half lds_m[4][16][40];
  __shared__ int lds_idx[4][IDXCAP];
  __shared__ int lds_nd[4][32];          // [0..15]=noff, [16..31]=deg
  const int t = threadIdx.x;
  const int w = t >> 6, l = t & 63;
  const int d = l & 31, half = l >> 5;
  const int q  = d >> 3;        // edge subgroup 0..3
  const int r8 = d & 7;         // dim-quad index: dims 4*r8 .. 4*r8+3
  const int n0 = blockIdx.x*64 + w*16;
  const float4* WmP = (const float4*)(Wall + OFF_WMT);
  const __half* rowbase = curh + 4*r8;   // per-lane fixed dim offset
  // ---- stage node meta + edge indices (wave-private; in-order DS pipe) ----
  if(l < 16){
    lds_nd[w][l]    = noff[n0+l];
    lds_nd[w][16+l] = deg[n0+l];
  }
  int s_begin = lds_nd[w][0];
  int total   = lds_nd[w][15] + lds_nd[w][31] - s_begin;
  int tc = total < IDXCAP ? total : IDXCAP;
  for(int i=l; i<tc; i+=64) lds_idx[w][i] = csr[s_begin+i];
  // ---- phase 1 ----
  if(total <= IDXCAP){
    // paired phases: nodes iA=4pp+half and iB=4pp+2+half gathered concurrently
    for(int pp=0;pp<4;pp++){
      int iA = 4*pp + half, iB = iA + 2;
      int sA = lds_nd[w][iA] - s_begin, lA = lds_nd[w][16+iA];
      int sB = lds_nd[w][iB] - s_begin, lB = lds_nd[w][16+iB];
      const int* ipA = &lds_idx[w][sA];
      const int* ipB = &lds_idx[w][sB];
      float aA0=0.f,aA1=0.f,aA2=0.f,aA3=0.f;
      float aB0=0.f,aB1=0.f,aB2=0.f,aB3=0.f;
      int ml = lA > lB ? lA : lB;
      for(int i=0; i<ml; i+=32){
        int rA = lA - i, rB = lB - i;
        if(rA > 0) gbatch(ipA, i, rA, rowbase, q, aA0,aA1,aA2,aA3);
        if(rB > 0) gbatch(ipB, i, rB, rowbase, q, aB0,aB1,aB2,aB3);
      }
      #pragma unroll
      for(int off=8; off<=16; off<<=1){
        aA0 += __shfl_xor(aA0, off, 32); aA1 += __shfl_xor(aA1, off, 32);
        aA2 += __shfl_xor(aA2, off, 32); aA3 += __shfl_xor(aA3, off, 32);
        aB0 += __shfl_xor(aB0, off, 32); aB1 += __shfl_xor(aB1, off, 32);
        aB2 += __shfl_xor(aB2, off, 32); aB3 += __shfl_xor(aB3, off, 32);
      }
      int lsrc = d >> 2;
      float vA0=__shfl(aA0,lsrc,32), vA1=__shfl(aA1,lsrc,32);
      float vA2=__shfl(aA2,lsrc,32), vA3=__shfl(aA3,lsrc,32);
      float vB0=__shfl(aB0,lsrc,32), vB1=__shfl(aB1,lsrc,32);
      float vB2=__shfl(aB2,lsrc,32), vB3=__shfl(aB3,lsrc,32);
      float accA = (d&1) ? ((d&2)? vA3 : vA1) : ((d&2)? vA2 : vA0);
      float accB = (d&1) ? ((d&2)? vB3 : vB1) : ((d&2)? vB2 : vB0);
      lds_acc[w][half][d]   = accA;
      lds_acc[w][2+half][d] = accB;
      const float4* acA = (const float4*)(&lds_acc[w][half][0]);
      const float4* acB = (const float4*)(&lds_acc[w][2+half][0]);
      float mA = 0.f, mB = 0.f;
      #pragma unroll
      for(int c=0;c<8;c++){
        float4 wv = WmP[c*32 + d];
        float4 avA = acA[c];
        float4 avB = acB[c];
        mA = __fmaf_rn(wv.x, avA.x, mA); mB = __fmaf_rn(wv.x, avB.x, mB);
        mA = __fmaf_rn(wv.y, avA.y, mA); mB = __fmaf_rn(wv.y, avB.y, mB);
        mA = __fmaf_rn(wv.z, avA.z, mA); mB = __fmaf_rn(wv.z, avB.z, mB);
        mA = __fmaf_rn(wv.w, avA.w, mA); mB = __fmaf_rn(wv.w, avB.w, mB);
      }
      lds_m[w][iA][d] = __float2half(fmaxf(mA, 0.f));
      lds_m[w][iB][d] = __float2half(fmaxf(mB, 0.f));
    }
  } else {
    // cold fallback (range > IDXCAP): sequential direct-csr path
    for(int p=0;p<8;p++){
      int ni = 2*p + half;
      int s0 = lds_nd[w][ni];
      int len = lds_nd[w][16+ni];
      float a0=0.f, a1=0.f, a2=0.f, a3=0.f;
      for(int i=0; i<len; i+=32){
        int rem = len - i;
        gbatch(csr + s0, i, rem, rowbase, q, a0,a1,a2,a3);
      }
      #pragma unroll
      for(int off=8; off<=16; off<<=1){
        a0 += __shfl_xor(a0, off, 32);
        a1 += __shfl_xor(a1, off, 32);
        a2 += __shfl_xor(a2, off, 32);
        a3 += __shfl_xor(a3, off, 32);
      }
      float v0 = __shfl(a0, d>>2, 32);
      float v1 = __shfl(a1, d>>2, 32);
      float v2 = __shfl(a2, d>>2, 32);
      float v3 = __shfl(a3, d>>2, 32);
      float accd = (d&1) ? ((d&2)? v3 : v1) : ((d&2)? v2 : v0);
      lds_acc[w][half][d] = accd;
      const float4* ac = (const float4*)(&lds_acc[w][half][0]);
      float m = 0.f;
      #pragma unroll
      for(int c=0;c<8;c++){
        float4 wv = WmP[c*32 + d];
        float4 av = ac[c];
        m = __fmaf_rn(wv.x, av.x, m);
        m = __fmaf_rn(wv.y, av.y, m);
        m = __fmaf_rn(wv.z, av.z, m);
        m = __fmaf_rn(wv.w, av.w, m);
      }
      lds_m[w][2*p+half][d] = __float2half(fmaxf(m, 0.f));
    }
  }
  // ---- phase 2 ----
  const int rowa = l & 15, grp = l >> 4;
  f16x4 Am0 = *(const f16x4*)((const void*)&lds_m[w][rowa][4*grp]);
  f16x4 Am1 = *(const f16x4*)((const void*)&lds_m[w][rowa][16 + 4*grp]);
  const __half* hrow = curh + (size_t)(n0 + rowa)*DD;
  f16x4 Ah0 = *(const f16x4*)((const void*)(hrow + 4*grp));
  f16x4 Ah1 = *(const f16x4*)((const void*)(hrow + 16 + 4*grp));
  const f16x4* Bf = (const f16x4*)F16;
  f32x4 Drz[4], Din[2], Dhn[2];
  #pragma unroll
  for(int jt=0;jt<4;jt++){
    f32x4 a = {0.f,0.f,0.f,0.f};
    a = __builtin_amdgcn_mfma_f32_16x16x16f16(Ah0, Bf[(12 + jt*2    )*64 + l], a, 0,0,0);
    a = __builtin_amdgcn_mfma_f32_16x16x16f16(Ah1, Bf[(12 + jt*2 + 1)*64 + l], a, 0,0,0);
    a = __builtin_amdgcn_mfma_f32_16x16x16f16(Am0, Bf[(     jt*2    )*64 + l], a, 0,0,0);
    a = __builtin_amdgcn_mfma_f32_16x16x16f16(Am1, Bf[(     jt*2 + 1)*64 + l], a, 0,0,0);
    Drz[jt] = a;
  }
  #pragma unroll
  for(int s=0;s<2;s++){
    int jt = 4 + s;
    f32x4 a = {0.f,0.f,0.f,0.f};
    f32x4 b = {0.f,0.f,0.f,0.f};
    a = __builtin_amdgcn_mfma_f32_16x16x16f16(Am0, Bf[(     jt*2    )*64 + l], a, 0,0,0);
    a = __builtin_amdgcn_mfma_f32_16x16x16f16(Am1, Bf[(     jt*2 + 1)*64 + l], a, 0,0,0);
    b = __builtin_amdgcn_mfma_f32_16x16x16f16(Ah0, Bf[(12 + jt*2    )*64 + l], b, 0,0,0);
    b = __builtin_amdgcn_mfma_f32_16x16x16f16(Ah1, Bf[(12 + jt*2 + 1)*64 + l], b, 0,0,0);
    Din[s] = a; Dhn[s] = b;
  }
  #pragma unroll
  for(int s=0;s<2;s++){
    int dd = 16*s + rowa;
    float br = Wall[OFF_BIHG+dd]      + Wall[OFF_BHHG+dd];
    float bz = Wall[OFF_BIHG+DD+dd]   + Wall[OFF_BHHG+DD+dd];
    float bi = Wall[OFF_BIHG+2*DD+dd];
    float bh = Wall[OFF_BHHG+2*DD+dd];
    #pragma unroll
    for(int r=0;r<4;r++){
      int node = n0 + grp*4 + r;
      float hv = __half2float(curh[(size_t)node*DD + dd]);
      float rr = sigm(Drz[s][r]   + br);
      float zz = sigm(Drz[2+s][r] + bz);
      float nn = tanhfast((Din[s][r] + bi) + rr*(Dhn[s][r] + bh));
      nxth[(size_t)node*DD + dd] = __float2half((1.f - zz)*nn + zz*hv);
    }
  }
}

// ---- Set2Set + readout: block g owns graph g; 1024 thr = 16 waves (r7 win) -------
#define MAXEV 1024
__global__ void __launch_bounds__(1024, 8) k_s2s(const float* __restrict__ Wall,
                       const __half* __restrict__ hstate, const int* __restrict__ goff,
                       void* __restrict__ op, const int* __restrict__ flag){
  int g = blockIdx.x, t = threadIdx.x;
  int l32 = t & 31, g32 = t >> 5;        // 32 row-groups of 32 lanes
  __shared__ float evb[MAXEV];
  __shared__ float red[32*33];           // pass3 transpose-reduce, padded
  __shared__ float wred[16];
  __shared__ float qs[64];
  __shared__ float xb[64];
  __shared__ float hb[3][32];
  __shared__ float gbuf[128];
  __shared__ float yb[32];
  __shared__ float bc_mx, bc_inv;
  int s0 = goff[g], s1 = goff[g+1];
  int len = s1 - s0;
  int lc = len < MAXEV ? len : MAXEV;
  if(t < 64) qs[t] = 0.f;
  if(t < 96) hb[t>>5][t&31] = 0.f;
  float c0=0.f, c1=0.f, c2v=0.f;           // cell states on threads 0..31
  __syncthreads();
  for(int it=0; it<6; it++){
    if(t<64) xb[t]=qs[t];
    __syncthreads();
    // ---- LSTM layer 0 (xdim 64) ----
    if(t<128){
      const float* WT = Wall + OFF_WIH0T; const float* UT = Wall + OFF_WHH0T;
      float gv = Wall[OFF_BIH0+t] + Wall[OFF_BHH0+t];
      #pragma unroll 8
      for(int k=0;k<64;k++) gv = __fmaf_rn(WT[k*128+t], xb[k], gv);
      #pragma unroll 8
      for(int k=0;k<32;k++) gv = __fmaf_rn(UT[k*128+t], hb[0][k], gv);
      gbuf[t]=gv;
    }
    __syncthreads();
    if(t<32){
      float iv=sigm(gbuf[t]), fv=sigm(gbuf[32+t]), gg=tanhfast(gbuf[64+t]), ov=sigm(gbuf[96+t]);
      float c = fv*c0 + iv*gg; c0=c;
      float h2 = ov*tanhfast(c);
      hb[0][t]=h2; xb[t]=h2;
    }
    __syncthreads();
    // ---- LSTM layers 1,2 (xdim 32) ----
    for(int l=1;l<3;l++){
      if(t<128){
        const float* WT = Wall + (l==1?OFF_WIH1T:OFF_WIH2T);
        const float* UT = Wall + (l==1?OFF_WHH1T:OFF_WHH2T);
        int bo=(l-1)*128;
        float gv = Wall[OFF_BIH12+bo+t] + Wall[OFF_BHH12+bo+t];
        #pragma unroll 8
        for(int k=0;k<32;k++) gv = __fmaf_rn(WT[k*128+t], xb[k], gv);
        #pragma unroll 8
        for(int k=0;k<32;k++) gv = __fmaf_rn(UT[k*128+t], hb[l][k], gv);
        gbuf[t]=gv;
      }
      __syncthreads();
      if(t<32){
        float cp = (l==1)?c1:c2v;
        float iv=sigm(gbuf[t]), fv=sigm(gbuf[32+t]), gg=tanhfast(gbuf[64+t]), ov=sigm(gbuf[96+t]);
        float c = fv*cp + iv*gg;
        if(l==1) c1=c; else c2v=c;
        float h2 = ov*tanhfast(c);
        hb[l][t]=h2; xb[t]=h2;
      }
      __syncthreads();
    }
    float q = xb[l32];                     // layer-2 h, per-lane
    // ---- pass 1: logits + max ----
    float lmax = -INFINITY;
    for(int i=g32; i<len; i+=32){
      float v = __half2float(hstate[(size_t)(s0+i)*DD+l32])*q;
      #pragma unroll
      for(int o=16;o>0;o>>=1) v += __shfl_xor(v,o,32);
      if(i<lc && l32==0) evb[i]=v;
      lmax = fmaxf(lmax, v);
    }
    lmax = fmaxf(lmax, __shfl_xor(lmax, 32, 64));
    if((t&63)==0) wred[t>>6]=lmax;
    __syncthreads();
    if(t==0){ float m=wred[0];
      #pragma unroll
      for(int k=1;k<16;k++) m=fmaxf(m,wred[k]);
      bc_mx=m; }
    __syncthreads();
    float mx = bc_mx;
    // ---- pass 2: exp + sum; cache exp into evb ----
    float sm=0.f;
    for(int i=t;i<len;i+=1024){
      float v;
      if(i<lc) v=evb[i];
      else { v=0.f; for(int k=0;k<DD;k++) v += __half2float(hstate[(size_t)(s0+i)*DD+k])*xb[k]; }
      float e = __expf(v-mx);
      if(i<lc) evb[i]=e;
      sm += e;
    }
    #pragma unroll
    for(int o=32;o>0;o>>=1) sm += __shfl_xor(sm,o,64);
    if((t&63)==0) wred[t>>6]=sm;
    __syncthreads();
    if(t==0){ float s=0.f;
      #pragma unroll
      for(int k=0;k<16;k++) s+=wred[k];
      bc_inv = (s>0.f) ? 1.f/s : 0.f; }
    __syncthreads();
    float inv = bc_inv;
    // ---- pass 3: weighted sum ----
    float acc=0.f;
    for(int i=g32;i<len;i+=32){
      float fv = __half2float(hstate[(size_t)(s0+i)*DD+l32]);
      float wgt;
      if(i<lc) wgt=evb[i];
      else { float vv=fv*q;
             #pragma unroll
             for(int o=16;o>0;o>>=1) vv += __shfl_xor(vv,o,32);
             wgt=__expf(vv-mx); }
      acc = __fmaf_rn(wgt, fv, acc);
    }
    red[g32*33+l32]=acc; __syncthreads();
    if(t<32){
      float s=0.f;
      #pragma unroll
      for(int k=0;k<32;k++) s+=red[k*33+t];
      qs[32+t]=s*inv; qs[t]=xb[t];
    }
    __syncthreads();
  }
  // ---- readout MLP ----
  if(t<32){
    const float* W1 = Wall+OFF_WR1T;
    float s = Wall[OFF_BR1+t];
    #pragma unroll 8
    for(int k=0;k<64;k++) s = __fmaf_rn(W1[k*32+t], qs[k], s);
    yb[t]=fmaxf(s,0.f);
  }
  __syncthreads();
  if(t<32){
    const float* W2 = Wall+OFF_WR2T;
    float o = Wall[OFF_BR2+t];
    #pragma unroll 8
    for(int k=0;k<32;k++) o = __fmaf_rn(W2[k*32+t], yb[k], o);
    if(flag[0]) ((__hip_bfloat16*)op)[g*32+t]=__float2bfloat16(o);
    else        ((float*)op)[g*32+t]=o;
  }
}

extern "C" void kernel_launch(void* const* d_in, const int* in_sizes, int n_in,
                              void* d_out, int out_size, void* d_ws, size_t ws_size,
                              hipStream_t stream) {
  const int* nt  = (const int*)d_in[0];
  const int* src = (const int*)d_in[1];
  const int* dst = (const int*)d_in[2];
  const int* gid = (const int*)d_in[3];
  float* W = (float*)d_ws;
  char* base = (char*)d_ws;
  __half* F16 = (__half*)(base + F16_BYTE);
  __half* h0 = (__half*)(base + H0_BYTE);
  __half* h1 = (__half*)(base + H1_BYTE);
  int* I = (int*)(base + INT_BASE);
  int* deg=I+I_DEG; int* noff=I+I_NOFF; int* cnt=I+I_CNT;
  int* goff=I+I_GOFF; int* csr=I+I_CSR;
  int* flag=I+I_FLAG; int* total=I+I_TOT; int* bbase=I+I_BBASE;
  // bucketed edge temp reuses h1 (E ints = 12.8 MB); h1 is first written by
  // k_step step 0, strictly after k_bfine completes. Rebuilt every launch.
  int* bucketed = (int*)h1;

  k_detect<<<1,64,0,stream>>>((const unsigned int*)d_in[4], flag);

  PrepArgs pa;
  const int sidx[22]={4,6,10,11,14,15,18,19,21,23, 5,7,8,9,12,13,16,16,17,17,20,22};
  const int offs[22]={OFF_EMB,OFF_B0,OFF_BIHG,OFF_BHHG,OFF_BIH0,OFF_BHH0,OFF_BIH12,
                      OFF_BHH12,OFF_BR1,OFF_BR2, OFF_W0T,OFF_WMT,OFF_WIHGT,OFF_WHHGT,
                      OFF_WIH0T,OFF_WHH0T,OFF_WIH1T,OFF_WIH2T,OFF_WHH1T,OFF_WHH2T,
                      OFF_WR1T,OFF_WR2T};
  const int szs[22]={3232,32,96,96,128,128,256,256,32,32, 1024,1024,3072,3072,
                     8192,4096,4096,4096,4096,4096,2048,1024};
  // Wm chunk-packed fp32 (float4 matvec); Wih_g/Whh_g plain [96][32] (k_prep16 source)
  const int trR[22]={0,0,0,0,0,0,0,0,0,0, 32,0,0,0,128,128,128,128,128,128,32,32};
  const int pkv[22]={0,0,0,0,0,0,0,0,0,0, 0,32,0,0,0,0,0,0,0,0,0,0};
  const int sof[22]={0,0,0,0,0,0,0,0,0,0, 0,0,0,0,0,0,0,4096,0,4096,0,0};
  for(int i=0;i<22;i++){ pa.s[i]=d_in[sidx[i]]; pa.off[i]=offs[i]; pa.sz[i]=szs[i];
                         pa.trR[i]=trR[i]; pa.soff[i]=sof[i]; pa.pk[i]=pkv[i]; }
  hipLaunchKernelGGL(k_prep, dim3(32,22), dim3(256), 0, stream, pa, W, flag);
  k_prep16<<<24,256,0,stream>>>(W, F16);

  k_lin0<<<782,256,0,stream>>>(nt, W, h0);
  // ---- CSR build v2 (no global atomics, no memset) ----
  k_bcnt<<<NBLKA,256,0,stream>>>(dst, cnt);
  k_bscan1<<<NBUCK,256,0,stream>>>(cnt, total);
  k_bscan2<<<1,1024,0,stream>>>(total, bbase);
  k_bscat<<<NBLKA,256,0,stream>>>(src, dst, cnt, bbase, bucketed);
  k_goff<<<3,256,0,stream>>>(gid, goff);
  k_bfine<<<NBUCK,256,0,stream>>>(bucketed, bbase, deg, noff, csr);

  // 6 MP steps on fp16 double-buffered state (even count -> final state in h0)
  __half* curh = h0; __half* nxth = h1;
  for(int s=0;s<6;s++){
    k_step<<<3125,256,0,stream>>>(W, F16, noff, deg, csr, curh, nxth);
    __half* tmp = curh; curh = nxth; nxth = tmp;
  }
  // whole Set2Set + readout in one launch (block g == graph g, fully independent)
  k_s2s<<<B_,1024,0,stream>>>(W, curh, goff, d_out, flag);
}